// Round 2
// baseline (5897.495 us; speedup 1.0000x reference)
//
#include <hip/hip_runtime.h>

#define NN 1024
#define CC 256

// ---- output offsets (floats) ----
constexpr size_t OUT_G2P = 8ull * NN * NN;
constexpr size_t OUT_X1  = 16ull * NN * NN;
constexpr size_t OUT_X2  = OUT_X1 + 8ull * NN * CC;
constexpr size_t OUT_L   = OUT_X2 + 8ull * NN * CC;

// ---- workspace offsets (floats) ----
constexpr size_t OFF_ALU    = 0;                        // 16M floats
constexpr size_t OFF_LOGACC = 16ull * NN * NN;          // 256
constexpr size_t OFF_PIV    = OFF_LOGACC + 256;         // 4096 ints (perm lists)
constexpr size_t OFF_DEG    = OFF_PIV + 4096;           // 16384
constexpr size_t OFF_R2N    = OFF_DEG + 16384;          // 2097152
constexpr size_t OFF_LR2    = OFF_R2N + 2097152;        // 2097152
constexpr size_t OFF_LR1    = OFF_LR2 + 2097152;        // 32768
constexpr size_t OFF_X1P    = OFF_LR1 + 32768;          // 32768
constexpr size_t OFF_CS1    = OFF_X1P + 32768;          // 256
constexpr size_t OFF_CS2    = OFF_CS1 + 256;            // 2048
constexpr size_t OFF_BNP    = OFF_CS2 + 2048;           // 32768
constexpr size_t OFF_BNS    = OFF_BNP + 32768;          // 1024
constexpr size_t OFF_WSP    = OFF_BNS + 1024;           // 2048

// perm-list layout inside OFF_PIV (ints): PS[16][64], TD[16][64], TS[16][64], TC[16]
#define PRM_PS 0
#define PRM_TD 1024
#define PRM_TS 2048
#define PRM_TC 3072

// ============ pooling (pair tiles): Gp = 0.5*(W + W^T), A = Gp + 1e-3 I ============
__global__ __launch_bounds__(256) void pool_pair_k(const float* __restrict__ G1,
    const float* __restrict__ G2, const float* __restrict__ U1,
    const float* __restrict__ U2, float* __restrict__ out, float* __restrict__ Alu) {
  int mat = blockIdx.z, g = mat >> 3, b = mat & 7;
  const float* G = (g ? G2 : G1) + (size_t)b * NN * NN;
  const float* U = g ? U2 : U1;
  float* Gp = out + (size_t)mat * NN * NN;
  float* A  = Alu + (size_t)mat * NN * NN;

  // decode pair (ti <= tj) from linear pair id
  int pid = blockIdx.x;
  int ti = 0, rem = pid;
  while (rem >= 16 - ti) { rem -= 16 - ti; ++ti; }
  int tj = ti + rem;

  int tc = threadIdx.x & 63, tr = threadIdx.x >> 6;
  __shared__ float Wa[64][65];
  __shared__ float Wb[64][65];
  #pragma unroll
  for (int s = 0; s < 16; ++s) {
    int r = s * 4 + tr;
    size_t ia = (size_t)(ti * 64 + r) * NN + tj * 64 + tc;
    size_t ib = (size_t)(tj * 64 + r) * NN + ti * 64 + tc;
    Wa[r][tc] = U[ia] * G[ia];
    Wb[r][tc] = U[ib] * G[ib];
  }
  __syncthreads();
  #pragma unroll
  for (int s = 0; s < 16; ++s) {
    int r = s * 4 + tr;
    float o1 = 0.5f * (Wa[r][tc] + Wb[tc][r]);
    size_t idx1 = (size_t)(ti * 64 + r) * NN + tj * 64 + tc;
    Gp[idx1] = o1;
    A[idx1] = o1 + ((ti == tj && r == tc) ? 1e-3f : 0.0f);
    if (ti != tj) {
      float o2 = 0.5f * (Wb[r][tc] + Wa[tc][r]);
      size_t idx2 = (size_t)(tj * 64 + r) * NN + ti * 64 + tc;
      Gp[idx2] = o2;
      A[idx2] = o2;
    }
  }
}

// ============ deg[b,i] = sum_j Gp[b,i,j] ============
__global__ __launch_bounds__(256) void deg_k(const float* __restrict__ out,
                                             float* __restrict__ deg) {
  int wid = threadIdx.x >> 6, lane = threadIdx.x & 63;
  int row = blockIdx.x * 4 + wid;
  const float* Gp = out + (size_t)row * NN;
  float s = 0.f;
  for (int k = lane; k < NN; k += 64) s += Gp[k];
  #pragma unroll
  for (int o = 32; o; o >>= 1) s += __shfl_down(s, o, 64);
  if (!lane) deg[row] = s;
}

// ============ batchnorm ============
__global__ __launch_bounds__(256) void bn_partial_k(const float* __restrict__ R2,
                                                    float* __restrict__ part) {
  int w = blockIdx.x, c = threadIdx.x;
  float s = 0.f, s2 = 0.f;
  for (int r = w * 128; r < (w + 1) * 128; ++r) {
    float x = R2[(size_t)r * CC + c];
    s += x; s2 += x * x;
  }
  part[w * 512 + c] = s;
  part[w * 512 + 256 + c] = s2;
}

__global__ __launch_bounds__(256) void bn_final_k(const float* __restrict__ part,
    const float* __restrict__ g, const float* __restrict__ bt, float* __restrict__ stats) {
  int c = threadIdx.x;
  float s = 0.f, s2 = 0.f;
  for (int w = 0; w < 64; ++w) { s += part[w * 512 + c]; s2 += part[w * 512 + 256 + c]; }
  float mu = s / 8192.0f, var = s2 / 8192.0f - mu * mu;
  stats[c] = mu;
  stats[256 + c] = rsqrtf(var + 1e-5f) * g[c];
  stats[512 + c] = bt[c];
}

__global__ __launch_bounds__(256) void bn_apply_k(const float* __restrict__ R2,
    const float* __restrict__ stats, float* __restrict__ R2n) {
  int c = threadIdx.x;
  size_t i = (size_t)blockIdx.x * CC + c;
  R2n[i] = (R2[i] - stats[c]) * stats[256 + c] + stats[512 + c];
}

// ============ column sums ============
__global__ __launch_bounds__(256) void colsum2_k(const float* __restrict__ R2n,
                                                 float* __restrict__ cs2) {
  int b = blockIdx.x, c = threadIdx.x;
  float s = 0.f;
  for (int n = 0; n < NN; ++n) s += R2n[((size_t)b * NN + n) * CC + c];
  cs2[b * CC + c] = s;
}

__global__ __launch_bounds__(64) void colsum1_k(const float* __restrict__ R1,
                                                float* __restrict__ cs1) {
  int t = threadIdx.x;
  if (t >= 32) return;
  int b = t >> 2, c = t & 3;
  float s = 0.f;
  for (int n = 0; n < NN; ++n) s += R1[((size_t)b * NN + n) * 4 + c];
  cs1[b * 4 + c] = s;
}

// ============ LU panel NB=64: register-resident, partial pivoting ============
__global__ __launch_bounds__(256, 1) void lu_panel64_k(float* __restrict__ Alu, int p,
    float* __restrict__ logacc, int* __restrict__ prm) {
  const int mat = blockIdx.x;
  float* A = Alu + (size_t)mat * NN * NN;
  const int k0 = p * 64;
  const int tid = threadIdx.x;
  const int lane = tid & 63, wid = tid >> 6;

  __shared__ float urow[64];
  __shared__ float swapA[64];
  __shared__ float redv[4];
  __shared__ int   redi[4];
  __shared__ int   s_piv;
  __shared__ int   pvlist[64];
  __shared__ int   sperm[1024];
  __shared__ int   s_cnt;

  for (int i = tid; i < 1024; i += 256) sperm[i] = i;

  float preg[4][64];
  #pragma unroll
  for (int s = 0; s < 4; ++s) {
    const int i = k0 + tid + s * 256;
    if (i < NN) {
      const float4* Ar = reinterpret_cast<const float4*>(A + (size_t)i * NN + k0);
      #pragma unroll
      for (int c4 = 0; c4 < 16; ++c4) {
        float4 v = Ar[c4];
        preg[s][c4 * 4 + 0] = v.x; preg[s][c4 * 4 + 1] = v.y;
        preg[s][c4 * 4 + 2] = v.z; preg[s][c4 * 4 + 3] = v.w;
      }
    } else {
      #pragma unroll
      for (int c = 0; c < 64; ++c) preg[s][c] = 0.0f;
    }
  }

  float lsum = 0.0f;

  for (int j = 0; j < 64; ++j) {
    // pivot argmax over rows >= k0+j on current column (preg[.][0])
    float bv = -1.0f; int br = -1;
    #pragma unroll
    for (int s = 0; s < 4; ++s) {
      const int i = k0 + tid + s * 256;
      if (i < NN && i >= k0 + j) {
        const float v = fabsf(preg[s][0]);
        if (v > bv) { bv = v; br = i; }
      }
    }
    #pragma unroll
    for (int o = 32; o; o >>= 1) {
      const float ov = __shfl_down(bv, o, 64);
      const int   oi = __shfl_down(br, o, 64);
      if (ov > bv) { bv = ov; br = oi; }
    }
    if (lane == 0) { redv[wid] = bv; redi[wid] = br; }
    __syncthreads();                              // B1
    if (tid == 0) {
      float fv = redv[0]; int fi = redi[0];
      #pragma unroll
      for (int wq = 1; wq < 4; ++wq)
        if (redv[wq] > fv) { fv = redv[wq]; fi = redi[wq]; }
      s_piv = fi;
      pvlist[j] = fi;
      lsum += logf(fmaxf(fv, 1e-37f));
    }
    __syncthreads();                              // B2
    const int pr = s_piv;

    // swap streamed L-history (cols k0..k0+j-1, in global) between rows k0+j, pr
    if (tid < j && pr != k0 + j) {
      size_t a1 = (size_t)(k0 + j) * NN + k0 + tid;
      size_t a2 = (size_t)pr * NN + k0 + tid;
      float t1 = A[a1], t2 = A[a2];
      A[a1] = t2; A[a2] = t1;
    }

    // register row swap via LDS: row k0+j -> swapA ; row pr -> urow
    {
      const int tb = (pr - k0) & 255;
      const int sb = (pr - k0) >> 8;
      if (tid == j) {
        #pragma unroll
        for (int c = 0; c < 64; ++c) swapA[c] = preg[0][c];
      }
      if (tid == tb) {
        #pragma unroll
        for (int s = 0; s < 4; ++s) if (s == sb) {
          #pragma unroll
          for (int c = 0; c < 64; ++c) urow[c] = preg[s][c];
        }
      }
      __syncthreads();                            // B3
      if (tid == tb && pr != k0 + j) {
        #pragma unroll
        for (int s = 0; s < 4; ++s) if (s == sb) {
          #pragma unroll
          for (int c = 0; c < 64; ++c) preg[s][c] = swapA[c];
        }
      }
    }

    // prefetch urow to registers (b128)
    float ur[64];
    #pragma unroll
    for (int c4 = 0; c4 < 16; ++c4) {
      float4 t = *reinterpret_cast<const float4*>(&urow[c4 * 4]);
      ur[c4 * 4 + 0] = t.x; ur[c4 * 4 + 1] = t.y;
      ur[c4 * 4 + 2] = t.z; ur[c4 * 4 + 3] = t.w;
    }

    // stream U row
    const int W = 64 - j;
    if (tid < W) A[(size_t)(k0 + j) * NN + (k0 + j) + tid] = ur[tid];

    // rank-1 update + column shift; stream L multipliers
    const float pv = ur[0];
    const float pvs = (fabsf(pv) < 1e-37f) ? copysignf(1e-37f, pv) : pv;
    const float ipv = 1.0f / pvs;
    float lmul[4];
    #pragma unroll
    for (int s = 0; s < 4; ++s) {
      const int i = k0 + tid + s * 256;
      const bool act = (i < NN) && (i > k0 + j);
      lmul[s] = act ? preg[s][0] * ipv : 0.0f;
      if (act) A[(size_t)i * NN + (k0 + j)] = lmul[s];
    }
    #pragma unroll
    for (int c = 1; c < 64; ++c) {
      const float u = ur[c];
      #pragma unroll
      for (int s = 0; s < 4; ++s) preg[s][c - 1] = preg[s][c] - lmul[s] * u;
    }
  }

  if (tid == 0) {
    if (p == 0) logacc[mat] = lsum;
    else        logacc[mat] += lsum;
  }

  // net row permutation for trailing columns
  __syncthreads();
  if (tid == 0) {
    s_cnt = 0;
    for (int s = 0; s < 64; ++s) {
      int a = k0 + s, b = pvlist[s];
      int t = sperm[a]; sperm[a] = sperm[b]; sperm[b] = t;
    }
  }
  __syncthreads();
  if (tid < 64) prm[PRM_PS + mat * 64 + tid] = sperm[k0 + tid];
  for (int i = k0 + 64 + tid; i < 1024; i += 256) {
    if (sperm[i] != i) {
      int sl = atomicAdd(&s_cnt, 1);
      prm[PRM_TD + mat * 64 + sl] = i;
      prm[PRM_TS + mat * 64 + sl] = sperm[i];
    }
  }
  __syncthreads();
  if (tid == 0) prm[PRM_TC + mat] = s_cnt;
}

// ============ perm-gather swap + TRSM (U12 = L11^-1 P A12), width 64 ============
__global__ __launch_bounds__(256, 1) void lu_swaptrsm64_k(float* __restrict__ Alu,
    int p, const int* __restrict__ prm) {
  int mat = blockIdx.y;
  float* A = Alu + (size_t)mat * NN * NN;
  int k0 = p * 64;
  int col = k0 + 64 + blockIdx.x * 256 + threadIdx.x;
  __shared__ float L11[64][65];
  __shared__ int ps[64], td[64], ts[64];
  __shared__ int s_nc;
  for (int t = threadIdx.x; t < 64 * 64; t += 256) {
    int r = t >> 6, c = t & 63;
    L11[r][c] = A[(size_t)(k0 + r) * NN + k0 + c];
  }
  if (threadIdx.x < 64) {
    ps[threadIdx.x] = prm[PRM_PS + mat * 64 + threadIdx.x];
    td[threadIdx.x] = prm[PRM_TD + mat * 64 + threadIdx.x];
    ts[threadIdx.x] = prm[PRM_TS + mat * 64 + threadIdx.x];
  }
  if (threadIdx.x == 0) s_nc = prm[PRM_TC + mat];
  __syncthreads();
  if (col >= NN) return;
  const int nc = s_nc;

  // gather ALL sources (old values) before any writes
  float u[64], tv[64];
  #pragma unroll
  for (int r = 0; r < 64; ++r) u[r] = A[(size_t)ps[r] * NN + col];
  #pragma unroll
  for (int i = 0; i < 64; ++i) tv[i] = (i < nc) ? A[(size_t)ts[i] * NN + col] : 0.0f;
  // scatter trailing permuted rows
  #pragma unroll
  for (int i = 0; i < 64; ++i) if (i < nc) A[(size_t)td[i] * NN + col] = tv[i];
  // trsm (unit-lower)
  #pragma unroll
  for (int l = 0; l < 64; ++l) {
    float ul = u[l];
    #pragma unroll
    for (int r = l + 1; r < 64; ++r) u[r] -= L11[r][l] * ul;
  }
  #pragma unroll
  for (int r = 0; r < 64; ++r) A[(size_t)(k0 + r) * NN + col] = u[r];
}

// ============ Schur update: A22 -= L21 @ U12 (128x128 tile, K=64) ============
__global__ __launch_bounds__(256) void lu_gemm64_k(float* __restrict__ Alu, int p) {
  int mat = blockIdx.z;
  float* A = Alu + (size_t)mat * NN * NN;
  int k0 = p * 64;
  int base = k0 + 64;
  int r0 = base + blockIdx.y * 128, c0 = base + blockIdx.x * 128;
  __shared__ float Ls[128][36];
  __shared__ float Us[32][132];
  int tid = threadIdx.x, tx = tid & 15, ty = tid >> 4;
  float acc[8][8] = {};
  for (int kk = 0; kk < 64; kk += 32) {
    for (int t = tid; t < 1024; t += 256) {
      int r = t >> 3, cc4 = (t & 7) * 4;
      float4 v = {0.f, 0.f, 0.f, 0.f};
      if (r0 + r < NN)
        v = *reinterpret_cast<const float4*>(A + (size_t)(r0 + r) * NN + k0 + kk + cc4);
      *reinterpret_cast<float4*>(&Ls[r][cc4]) = v;
    }
    for (int t = tid; t < 1024; t += 256) {
      int r = t >> 5, cc4 = (t & 31) * 4;
      float4 v = {0.f, 0.f, 0.f, 0.f};
      if (c0 + cc4 < NN)
        v = *reinterpret_cast<const float4*>(A + (size_t)(k0 + kk + r) * NN + c0 + cc4);
      *reinterpret_cast<float4*>(&Us[r][cc4]) = v;
    }
    __syncthreads();
    #pragma unroll 8
    for (int l = 0; l < 32; ++l) {
      float a[8], bv[8];
      #pragma unroll
      for (int q = 0; q < 4; ++q) {
        a[q]     = Ls[ty * 4 + q][l];
        a[q + 4] = Ls[64 + ty * 4 + q][l];
      }
      #pragma unroll
      for (int r = 0; r < 4; ++r) {
        bv[r]     = Us[l][tx * 4 + r];
        bv[r + 4] = Us[l][64 + tx * 4 + r];
      }
      #pragma unroll
      for (int q = 0; q < 8; ++q)
        #pragma unroll
        for (int r = 0; r < 8; ++r) acc[q][r] += a[q] * bv[r];
    }
    __syncthreads();
  }
  #pragma unroll
  for (int q = 0; q < 8; ++q) {
    int rr = r0 + ((q < 4) ? ty * 4 + q : 64 + ty * 4 + q - 4);
    if (rr < NN) {
      #pragma unroll
      for (int r = 0; r < 8; ++r) {
        int cc = c0 + ((r < 4) ? tx * 4 + r : 64 + tx * 4 + r - 4);
        if (cc < NN) A[(size_t)rr * NN + cc] -= acc[q][r];
      }
    }
  }
}

// ============ thin GEMV: C=4 path ============
__global__ __launch_bounds__(256) void gemv4_k(const float* __restrict__ Gp,
    const float* __restrict__ V, const float* __restrict__ deg,
    const float* __restrict__ cs, float* __restrict__ O, int mode) {
  int wid = threadIdx.x >> 6, lane = threadIdx.x & 63;
  int row = blockIdx.x * 4 + wid;
  int b = row >> 10, i = row & 1023;
  const float* Gr = Gp + (size_t)b * NN * NN + (size_t)i * NN;
  const float* Vb = V + (size_t)b * NN * 4;
  float a0 = 0.f, a1 = 0.f, a2 = 0.f, a3 = 0.f;
  for (int k = lane; k < NN; k += 64) {
    float g = Gr[k];
    float4 v = *reinterpret_cast<const float4*>(Vb + (size_t)k * 4);
    a0 += g * v.x; a1 += g * v.y; a2 += g * v.z; a3 += g * v.w;
  }
  #pragma unroll
  for (int o = 32; o; o >>= 1) {
    a0 += __shfl_down(a0, o, 64); a1 += __shfl_down(a1, o, 64);
    a2 += __shfl_down(a2, o, 64); a3 += __shfl_down(a3, o, 64);
  }
  if (lane == 0) {
    float4 v = *reinterpret_cast<const float4*>(Vb + (size_t)i * 4);
    float dg = deg[row];
    float r0 = dg * v.x - a0, r1 = dg * v.y - a1;
    float r2 = dg * v.z - a2, r3 = dg * v.w - a3;
    if (mode) {
      r0 = 2.f * r0 + v.x + cs[b * 4 + 0];
      r1 = 2.f * r1 + v.y + cs[b * 4 + 1];
      r2 = 2.f * r2 + v.z + cs[b * 4 + 2];
      r3 = 2.f * r3 + v.w + cs[b * 4 + 3];
    }
    float4 o4 = {r0, r1, r2, r3};
    *reinterpret_cast<float4*>(O + (size_t)row * 4) = o4;
  }
}

// ============ L-apply GEMM (C=256): O = deg*V - Gp@V [m0]; 2*that + V + cs [m1] ============
__global__ __launch_bounds__(256) void lgemm2_k(const float* __restrict__ Gp,
    const float* __restrict__ V, const float* __restrict__ deg,
    const float* __restrict__ cs, float* __restrict__ O, int mode) {
  int b = blockIdx.y;
  int i0 = blockIdx.x * 16;
  const float* G = Gp + (size_t)b * NN * NN;
  const float* Vb = V + (size_t)b * NN * CC;
  __shared__ float Gs[16][36];
  __shared__ float Vs[32][256];
  int tid = threadIdx.x;
  int c4 = (tid & 63) * 4, rg = tid >> 6;
  float acc[4][4] = {};
  for (int kk = 0; kk < NN; kk += 32) {
    if (tid < 128) {
      int r = tid >> 3, cc4 = (tid & 7) * 4;
      float4 g = *reinterpret_cast<const float4*>(G + (size_t)(i0 + r) * NN + kk + cc4);
      *reinterpret_cast<float4*>(&Gs[r][cc4]) = g;
    }
    #pragma unroll
    for (int it = 0; it < 8; ++it) {
      int idx = tid + it * 256;
      int r = idx >> 6, vc4 = (idx & 63) * 4;
      float4 v = *reinterpret_cast<const float4*>(Vb + (size_t)(kk + r) * CC + vc4);
      *reinterpret_cast<float4*>(&Vs[r][vc4]) = v;
    }
    __syncthreads();
    #pragma unroll
    for (int k4 = 0; k4 < 8; ++k4) {
      float4 g0 = *reinterpret_cast<const float4*>(&Gs[rg * 4 + 0][k4 * 4]);
      float4 g1 = *reinterpret_cast<const float4*>(&Gs[rg * 4 + 1][k4 * 4]);
      float4 g2 = *reinterpret_cast<const float4*>(&Gs[rg * 4 + 2][k4 * 4]);
      float4 g3 = *reinterpret_cast<const float4*>(&Gs[rg * 4 + 3][k4 * 4]);
      float4 v0 = *reinterpret_cast<const float4*>(&Vs[k4 * 4 + 0][c4]);
      float4 v1 = *reinterpret_cast<const float4*>(&Vs[k4 * 4 + 1][c4]);
      float4 v2 = *reinterpret_cast<const float4*>(&Vs[k4 * 4 + 2][c4]);
      float4 v3 = *reinterpret_cast<const float4*>(&Vs[k4 * 4 + 3][c4]);
      float ga[4][4] = {{g0.x, g0.y, g0.z, g0.w}, {g1.x, g1.y, g1.z, g1.w},
                        {g2.x, g2.y, g2.z, g2.w}, {g3.x, g3.y, g3.z, g3.w}};
      float va[4][4] = {{v0.x, v0.y, v0.z, v0.w}, {v1.x, v1.y, v1.z, v1.w},
                        {v2.x, v2.y, v2.z, v2.w}, {v3.x, v3.y, v3.z, v3.w}};
      #pragma unroll
      for (int kq = 0; kq < 4; ++kq)
        #pragma unroll
        for (int q = 0; q < 4; ++q)
          #pragma unroll
          for (int r = 0; r < 4; ++r) acc[q][r] += ga[q][kq] * va[kq][r];
    }
    __syncthreads();
  }
  #pragma unroll
  for (int q = 0; q < 4; ++q) {
    int i = i0 + rg * 4 + q;
    float dg = deg[b * NN + i];
    float4 vv = *reinterpret_cast<const float4*>(Vb + (size_t)i * CC + c4);
    float vo[4] = {vv.x, vv.y, vv.z, vv.w};
    float res[4];
    #pragma unroll
    for (int r = 0; r < 4; ++r) res[r] = dg * vo[r] - acc[q][r];
    if (mode) {
      float4 cv = *reinterpret_cast<const float4*>(cs + b * CC + c4);
      float co[4] = {cv.x, cv.y, cv.z, cv.w};
      #pragma unroll
      for (int r = 0; r < 4; ++r) res[r] = 2.f * res[r] + vo[r] + co[r];
    }
    float4 o4 = {res[0], res[1], res[2], res[3]};
    *reinterpret_cast<float4*>(O + ((size_t)b * NN + i) * CC + c4) = o4;
  }
}

// ============ conv1d: [B,N,4] -> [B,N,256], K=5, pad 2 ============
__global__ __launch_bounds__(256) void conv_k(const float* __restrict__ xp,
    const float* __restrict__ w, const float* __restrict__ bias,
    float* __restrict__ x1out) {
  int bn = blockIdx.x;
  int b = bn >> 10, n = bn & 1023;
  int co = threadIdx.x;
  __shared__ float xs[5][4];
  if (threadIdx.x < 20) {
    int k = threadIdx.x >> 2, ci = threadIdx.x & 3;
    int n2 = n + k - 2;
    xs[k][ci] = (n2 >= 0 && n2 < NN) ? xp[((size_t)b * NN + n2) * 4 + ci] : 0.0f;
  }
  __syncthreads();
  const float* wp = w + co * 20;
  float acc = bias[co];
  #pragma unroll
  for (int ci = 0; ci < 4; ++ci)
    #pragma unroll
    for (int k = 0; k < 5; ++k) acc += wp[ci * 5 + k] * xs[k][ci];
  x1out[((size_t)b * NN + n) * CC + co] = acc;
}

// ============ Wasserstein: bitonic sort 1024 per (b,c), sum |s1-s2| ============
__global__ __launch_bounds__(256) void wass_k(const float* __restrict__ x1,
    const float* __restrict__ x2, float* __restrict__ part) {
  int bc = blockIdx.x;
  int b = bc >> 8, c = bc & 255;
  __shared__ float s1[1024];
  __shared__ float s2[1024];
  __shared__ float red[256];
  int t = threadIdx.x;
  for (int q = 0; q < 4; ++q) {
    int n = t + q * 256;
    s1[n] = x1[((size_t)b * NN + n) * CC + c];
    s2[n] = x2[((size_t)b * NN + n) * CC + c];
  }
  __syncthreads();
  for (int k = 2; k <= 1024; k <<= 1) {
    for (int j = k >> 1; j > 0; j >>= 1) {
      #pragma unroll
      for (int q = 0; q < 2; ++q) {
        int idx = t + q * 256;
        int i = ((idx & ~(j - 1)) << 1) | (idx & (j - 1));
        int l = i | j;
        bool up = ((i & k) == 0);
        float a = s1[i], bvv = s1[l];
        if ((a > bvv) == up) { s1[i] = bvv; s1[l] = a; }
        a = s2[i]; bvv = s2[l];
        if ((a > bvv) == up) { s2[i] = bvv; s2[l] = a; }
      }
      __syncthreads();
    }
  }
  float s = 0.f;
  for (int q = 0; q < 4; ++q) {
    int n = t + q * 256;
    s += fabsf(s1[n] - s2[n]);
  }
  red[t] = s;
  __syncthreads();
  for (int o = 128; o; o >>= 1) {
    if (t < o) red[t] += red[t + o];
    __syncthreads();
  }
  if (!t) part[bc] = red[0];
}

// ============ finalize losses ============
__global__ __launch_bounds__(256) void finalize_k(const float* __restrict__ logacc,
    const float* __restrict__ part, float* __restrict__ out) {
  int t = threadIdx.x;
  __shared__ double red[256];
  double s = 0.0;
  for (int i = t; i < 2048; i += 256) s += (double)part[i];
  red[t] = s;
  __syncthreads();
  for (int o = 128; o; o >>= 1) {
    if (t < o) red[t] += red[t + o];
    __syncthreads();
  }
  if (!t) {
    double l1 = 0.0, l2 = 0.0;
    for (int i = 0; i < 8; ++i) { l1 += (double)logacc[i]; l2 += (double)logacc[8 + i]; }
    out[OUT_L + 0] = (float)(-l1 / 8.0);
    out[OUT_L + 1] = (float)(-l2 / 8.0);
    out[OUT_L + 2] = (float)(red[0] / 2097152.0);
  }
}

extern "C" void kernel_launch(void* const* d_in, const int* in_sizes, int n_in,
                              void* d_out, int out_size, void* d_ws, size_t ws_size,
                              hipStream_t stream) {
  (void)in_sizes; (void)n_in; (void)out_size; (void)ws_size;
  const float* G1 = (const float*)d_in[0];
  const float* G2 = (const float*)d_in[1];
  const float* R1 = (const float*)d_in[2];
  const float* R2 = (const float*)d_in[3];
  const float* U1 = (const float*)d_in[7];
  const float* U2 = (const float*)d_in[8];
  const float* CW = (const float*)d_in[9];
  const float* CB = (const float*)d_in[10];
  const float* BG = (const float*)d_in[11];
  const float* BBt = (const float*)d_in[12];
  float* out = (float*)d_out;
  float* ws = (float*)d_ws;

  float* Alu    = ws + OFF_ALU;
  float* logacc = ws + OFF_LOGACC;
  int*   prm    = (int*)(ws + OFF_PIV);
  float* deg    = ws + OFF_DEG;
  float* R2n    = ws + OFF_R2N;
  float* LR2    = ws + OFF_LR2;
  float* LR1    = ws + OFF_LR1;
  float* X1P    = ws + OFF_X1P;
  float* CS1    = ws + OFF_CS1;
  float* CS2    = ws + OFF_CS2;
  float* BNP    = ws + OFF_BNP;
  float* BNS    = ws + OFF_BNS;
  float* WSP    = ws + OFF_WSP;

  pool_pair_k<<<dim3(136, 1, 16), 256, 0, stream>>>(G1, G2, U1, U2, out, Alu);
  deg_k<<<4096, 256, 0, stream>>>(out, deg);

  bn_partial_k<<<64, 256, 0, stream>>>(R2, BNP);
  bn_final_k<<<1, 256, 0, stream>>>(BNP, BG, BBt, BNS);
  bn_apply_k<<<8192, 256, 0, stream>>>(R2, BNS, R2n);
  colsum2_k<<<8, 256, 0, stream>>>(R2n, CS2);
  colsum1_k<<<1, 64, 0, stream>>>(R1, CS1);

  // x1 path
  gemv4_k<<<2048, 256, 0, stream>>>(out, R1, deg, CS1, LR1, 0);
  gemv4_k<<<2048, 256, 0, stream>>>(out, LR1, deg, CS1, X1P, 1);
  conv_k<<<8192, 256, 0, stream>>>(X1P, CW, CB, out + OUT_X1);

  // x2 path
  lgemm2_k<<<dim3(64, 8), 256, 0, stream>>>(out + OUT_G2P, R2n, deg + 8192, CS2, LR2, 0);
  lgemm2_k<<<dim3(64, 8), 256, 0, stream>>>(out + OUT_G2P, LR2, deg + 8192, CS2, out + OUT_X2, 1);

  // blocked LU (NB=64) with partial pivoting on A = Gp + 1e-3 I (16 matrices)
  for (int p = 0; p < NN / 64; ++p) {
    lu_panel64_k<<<16, 256, 0, stream>>>(Alu, p, logacc, prm);
    int rem = NN - (p + 1) * 64;
    if (rem > 0) {
      lu_swaptrsm64_k<<<dim3((rem + 255) / 256, 16), 256, 0, stream>>>(Alu, p, prm);
      int mt = (rem + 127) / 128;
      lu_gemm64_k<<<dim3(mt, mt, 16), 256, 0, stream>>>(Alu, p);
    }
  }

  wass_k<<<2048, 256, 0, stream>>>(out + OUT_X1, out + OUT_X2, WSP);
  finalize_k<<<1, 256, 0, stream>>>(logacc, WSP, out);
}

// Round 3
// 4333.820 us; speedup vs baseline: 1.3608x; 1.3608x over previous
//
#include <hip/hip_runtime.h>

#define NN 1024
#define CC 256

// ---- output offsets (floats) ----
constexpr size_t OUT_G2P = 8ull * NN * NN;
constexpr size_t OUT_X1  = 16ull * NN * NN;
constexpr size_t OUT_X2  = OUT_X1 + 8ull * NN * CC;
constexpr size_t OUT_L   = OUT_X2 + 8ull * NN * CC;

// ---- workspace offsets (floats) ----
constexpr size_t OFF_ALU    = 0;                        // 16M floats
constexpr size_t OFF_LOGACC = 16ull * NN * NN;          // 256
constexpr size_t OFF_PIV    = OFF_LOGACC + 256;         // 4096 ints (perm lists)
constexpr size_t OFF_DEG    = OFF_PIV + 4096;           // 16384
constexpr size_t OFF_R2N    = OFF_DEG + 16384;          // 2097152
constexpr size_t OFF_LR2    = OFF_R2N + 2097152;        // 2097152
constexpr size_t OFF_LR1    = OFF_LR2 + 2097152;        // 32768
constexpr size_t OFF_X1P    = OFF_LR1 + 32768;          // 32768
constexpr size_t OFF_CS1    = OFF_X1P + 32768;          // 256
constexpr size_t OFF_CS2    = OFF_CS1 + 256;            // 2048
constexpr size_t OFF_BNP    = OFF_CS2 + 2048;           // 32768
constexpr size_t OFF_BNS    = OFF_BNP + 32768;          // 1024
constexpr size_t OFF_WSP    = OFF_BNS + 1024;           // 2048

// perm-list layout inside OFF_PIV (ints): PS[16][64], TD[16][64], TS[16][64], TC[16]
#define PRM_PS 0
#define PRM_TD 1024
#define PRM_TS 2048
#define PRM_TC 3072

// ============ pooling (pair tiles): Gp = 0.5*(W + W^T), A = Gp + 1e-3 I ============
__global__ __launch_bounds__(256) void pool_pair_k(const float* __restrict__ G1,
    const float* __restrict__ G2, const float* __restrict__ U1,
    const float* __restrict__ U2, float* __restrict__ out, float* __restrict__ Alu) {
  int mat = blockIdx.z, g = mat >> 3, b = mat & 7;
  const float* G = (g ? G2 : G1) + (size_t)b * NN * NN;
  const float* U = g ? U2 : U1;
  float* Gp = out + (size_t)mat * NN * NN;
  float* A  = Alu + (size_t)mat * NN * NN;

  int pid = blockIdx.x;
  int ti = 0, rem = pid;
  while (rem >= 16 - ti) { rem -= 16 - ti; ++ti; }
  int tj = ti + rem;

  int tc = threadIdx.x & 63, tr = threadIdx.x >> 6;
  __shared__ float Wa[64][65];
  __shared__ float Wb[64][65];
  #pragma unroll
  for (int s = 0; s < 16; ++s) {
    int r = s * 4 + tr;
    size_t ia = (size_t)(ti * 64 + r) * NN + tj * 64 + tc;
    size_t ib = (size_t)(tj * 64 + r) * NN + ti * 64 + tc;
    Wa[r][tc] = U[ia] * G[ia];
    Wb[r][tc] = U[ib] * G[ib];
  }
  __syncthreads();
  #pragma unroll
  for (int s = 0; s < 16; ++s) {
    int r = s * 4 + tr;
    float o1 = 0.5f * (Wa[r][tc] + Wb[tc][r]);
    size_t idx1 = (size_t)(ti * 64 + r) * NN + tj * 64 + tc;
    Gp[idx1] = o1;
    A[idx1] = o1 + ((ti == tj && r == tc) ? 1e-3f : 0.0f);
    if (ti != tj) {
      float o2 = 0.5f * (Wb[r][tc] + Wa[tc][r]);
      size_t idx2 = (size_t)(tj * 64 + r) * NN + ti * 64 + tc;
      Gp[idx2] = o2;
      A[idx2] = o2;
    }
  }
}

// ============ deg[b,i] = sum_j Gp[b,i,j] ============
__global__ __launch_bounds__(256) void deg_k(const float* __restrict__ out,
                                             float* __restrict__ deg) {
  int wid = threadIdx.x >> 6, lane = threadIdx.x & 63;
  int row = blockIdx.x * 4 + wid;
  const float* Gp = out + (size_t)row * NN;
  float s = 0.f;
  for (int k = lane; k < NN; k += 64) s += Gp[k];
  #pragma unroll
  for (int o = 32; o; o >>= 1) s += __shfl_down(s, o, 64);
  if (!lane) deg[row] = s;
}

// ============ batchnorm ============
__global__ __launch_bounds__(256) void bn_partial_k(const float* __restrict__ R2,
                                                    float* __restrict__ part) {
  int w = blockIdx.x, c = threadIdx.x;
  float s = 0.f, s2 = 0.f;
  for (int r = w * 128; r < (w + 1) * 128; ++r) {
    float x = R2[(size_t)r * CC + c];
    s += x; s2 += x * x;
  }
  part[w * 512 + c] = s;
  part[w * 512 + 256 + c] = s2;
}

__global__ __launch_bounds__(256) void bn_final_k(const float* __restrict__ part,
    const float* __restrict__ g, const float* __restrict__ bt, float* __restrict__ stats) {
  int c = threadIdx.x;
  float s = 0.f, s2 = 0.f;
  for (int w = 0; w < 64; ++w) { s += part[w * 512 + c]; s2 += part[w * 512 + 256 + c]; }
  float mu = s / 8192.0f, var = s2 / 8192.0f - mu * mu;
  stats[c] = mu;
  stats[256 + c] = rsqrtf(var + 1e-5f) * g[c];
  stats[512 + c] = bt[c];
}

__global__ __launch_bounds__(256) void bn_apply_k(const float* __restrict__ R2,
    const float* __restrict__ stats, float* __restrict__ R2n) {
  int c = threadIdx.x;
  size_t i = (size_t)blockIdx.x * CC + c;
  R2n[i] = (R2[i] - stats[c]) * stats[256 + c] + stats[512 + c];
}

// ============ column sums ============
__global__ __launch_bounds__(256) void colsum2_k(const float* __restrict__ R2n,
                                                 float* __restrict__ cs2) {
  int b = blockIdx.x, c = threadIdx.x;
  float s = 0.f;
  for (int n = 0; n < NN; ++n) s += R2n[((size_t)b * NN + n) * CC + c];
  cs2[b * CC + c] = s;
}

__global__ __launch_bounds__(64) void colsum1_k(const float* __restrict__ R1,
                                                float* __restrict__ cs1) {
  int t = threadIdx.x;
  if (t >= 32) return;
  int b = t >> 2, c = t & 3;
  float s = 0.f;
  for (int n = 0; n < NN; ++n) s += R1[((size_t)b * NN + n) * 4 + c];
  cs1[b * 4 + c] = s;
}

// ============ 32-col register sub-panel factorization (partial pivoting) ============
__device__ __forceinline__ void lu_sub32(float (&preg)[4][32], float* __restrict__ A,
    int k0, int off, int tid, int lane, int wid, float& lsum,
    float* urow, float* swapA, float* redv, int* redi, int* s_piv, int* sperm) {
  #pragma unroll 1
  for (int j = 0; j < 32; ++j) {
    const int rb = k0 + off + j;
    // pivot argmax over rows >= rb on current column (preg[.][0])
    float bv = -1.0f; int br = -1;
    #pragma unroll
    for (int s = 0; s < 4; ++s) {
      const int i = k0 + tid + s * 256;
      if (i < NN && i >= rb) {
        const float v = fabsf(preg[s][0]);
        if (v > bv) { bv = v; br = i; }
      }
    }
    #pragma unroll
    for (int o = 32; o; o >>= 1) {
      const float ov = __shfl_down(bv, o, 64);
      const int   oi = __shfl_down(br, o, 64);
      if (ov > bv) { bv = ov; br = oi; }
    }
    if (lane == 0) { redv[wid] = bv; redi[wid] = br; }
    __syncthreads();                              // B1
    if (tid == 0) {
      float fv = redv[0]; int fi = redi[0];
      #pragma unroll
      for (int w = 1; w < 4; ++w)
        if (redv[w] > fv) { fv = redv[w]; fi = redi[w]; }
      *s_piv = fi;
      lsum += logf(fmaxf(fv, 1e-37f));
      int t = sperm[rb]; sperm[rb] = sperm[fi]; sperm[fi] = t;
    }
    __syncthreads();                              // B2
    const int pr = *s_piv;

    // swap already-streamed L-history (global cols k0 .. k0+off+j-1)
    const int hist = off + j;
    if (tid < hist && pr != rb) {
      size_t a1 = (size_t)rb * NN + k0 + tid;
      size_t a2 = (size_t)pr * NN + k0 + tid;
      float t1 = A[a1], t2 = A[a2];
      A[a1] = t2; A[a2] = t1;
    }

    // register row swap via LDS: row rb (owner tid=off+j, s=0) <-> row pr
    const int ob = off + j;
    const int tb = (pr - k0) & 255, sb = (pr - k0) >> 8;
    if (tid == ob) {
      #pragma unroll
      for (int c = 0; c < 32; ++c) swapA[c] = preg[0][c];
    }
    if (tid == tb) {
      #pragma unroll
      for (int s = 0; s < 4; ++s) if (s == sb) {
        #pragma unroll
        for (int c = 0; c < 32; ++c) urow[c] = preg[s][c];
      }
    }
    __syncthreads();                              // B3
    if (tid == tb && pr != rb) {
      #pragma unroll
      for (int s = 0; s < 4; ++s) if (s == sb) {
        #pragma unroll
        for (int c = 0; c < 32; ++c) preg[s][c] = swapA[c];
      }
    }

    // pivot row to registers (static-indexed)
    float ur[32];
    #pragma unroll
    for (int c4 = 0; c4 < 8; ++c4) {
      float4 t = *reinterpret_cast<const float4*>(&urow[c4 * 4]);
      ur[c4 * 4 + 0] = t.x; ur[c4 * 4 + 1] = t.y;
      ur[c4 * 4 + 2] = t.z; ur[c4 * 4 + 3] = t.w;
    }

    // stream U row (from LDS: tid is runtime index)
    const int W = 32 - j;
    if (tid < W) A[(size_t)rb * NN + rb + tid] = urow[tid];

    // rank-1 update + column shift; stream L multipliers
    const float pv = ur[0];
    const float pvs = (fabsf(pv) < 1e-37f) ? copysignf(1e-37f, pv) : pv;
    const float ipv = 1.0f / pvs;
    float lm[4];
    #pragma unroll
    for (int s = 0; s < 4; ++s) {
      const int i = k0 + tid + s * 256;
      const bool act = (i < NN) && (i > rb);
      lm[s] = act ? preg[s][0] * ipv : 0.0f;
      if (act) A[(size_t)i * NN + rb] = lm[s];
    }
    #pragma unroll
    for (int c = 1; c < 32; ++c) {
      const float u = ur[c];
      #pragma unroll
      for (int s = 0; s < 4; ++s) preg[s][c - 1] = preg[s][c] - lm[s] * u;
    }
  }
}

// ============ LU panel NB=64 = two fused 32-col register sub-panels ============
__global__ __launch_bounds__(256, 1) void lu_panel64_k(float* __restrict__ Alu, int p,
    float* __restrict__ logacc, int* __restrict__ prm) {
  const int mat = blockIdx.x;
  float* A = Alu + (size_t)mat * NN * NN;
  const int k0 = p * 64;
  const int tid = threadIdx.x;
  const int lane = tid & 63, wid = tid >> 6;

  __shared__ __align__(16) float urow[32];
  __shared__ __align__(16) float swapA[32];
  __shared__ __align__(16) float U12s[32][36];
  __shared__ __align__(16) float L11s[32][36];
  __shared__ float redv[4];
  __shared__ int   redi[4];
  __shared__ int   s_piv;
  __shared__ int   sperm[1024];
  __shared__ int   s_cnt;

  for (int i = tid; i < 1024; i += 256) sperm[i] = i;
  __syncthreads();

  float preg[4][32];
  float lsum = 0.0f;

  // ---- Phase A: load + factor left 32 columns ----
  #pragma unroll
  for (int s = 0; s < 4; ++s) {
    const int i = k0 + tid + s * 256;
    if (i < NN) {
      const float4* Ar = reinterpret_cast<const float4*>(A + (size_t)i * NN + k0);
      #pragma unroll
      for (int c4 = 0; c4 < 8; ++c4) {
        float4 v = Ar[c4];
        preg[s][c4 * 4 + 0] = v.x; preg[s][c4 * 4 + 1] = v.y;
        preg[s][c4 * 4 + 2] = v.z; preg[s][c4 * 4 + 3] = v.w;
      }
    } else {
      #pragma unroll
      for (int c = 0; c < 32; ++c) preg[s][c] = 0.0f;
    }
  }

  lu_sub32(preg, A, k0, 0, tid, lane, wid, lsum, urow, swapA, redv, redi, &s_piv, sperm);

  // ---- Phase B: gather right strip (P applied), TRSM top, rank-32 update ----
  __syncthreads();
  #pragma unroll
  for (int s = 0; s < 4; ++s) {
    const int i = k0 + tid + s * 256;
    if (i < NN) {
      const int src = sperm[i];
      const float4* Ar = reinterpret_cast<const float4*>(A + (size_t)src * NN + k0 + 32);
      #pragma unroll
      for (int c4 = 0; c4 < 8; ++c4) {
        float4 v = Ar[c4];
        preg[s][c4 * 4 + 0] = v.x; preg[s][c4 * 4 + 1] = v.y;
        preg[s][c4 * 4 + 2] = v.z; preg[s][c4 * 4 + 3] = v.w;
      }
    } else {
      #pragma unroll
      for (int c = 0; c < 32; ++c) preg[s][c] = 0.0f;
    }
  }
  // stash strip-top rows + load L11 into LDS
  if (tid < 32) {
    #pragma unroll
    for (int c4 = 0; c4 < 8; ++c4) {
      float4 t = {preg[0][c4 * 4 + 0], preg[0][c4 * 4 + 1],
                  preg[0][c4 * 4 + 2], preg[0][c4 * 4 + 3]};
      *reinterpret_cast<float4*>(&U12s[tid][c4 * 4]) = t;
      float4 lv = *reinterpret_cast<const float4*>(A + (size_t)(k0 + tid) * NN + k0 + c4 * 4);
      *reinterpret_cast<float4*>(&L11s[tid][c4 * 4]) = lv;
    }
  }
  __syncthreads();
  // TRSM: per-lane column solve (thread c owns column c of the 32x32 top block)
  if (tid < 32) {
    float u[32];
    #pragma unroll
    for (int r = 0; r < 32; ++r) u[r] = U12s[r][tid];
    #pragma unroll
    for (int l = 0; l < 32; ++l) {
      const float ul = u[l];
      #pragma unroll
      for (int r = 0; r < 32; ++r)
        if (r > l) u[r] -= L11s[r][l] * ul;
    }
    #pragma unroll
    for (int r = 0; r < 32; ++r) U12s[r][tid] = u[r];
  }
  __syncthreads();
  // write U12 to global (row tid of strip-top)
  if (tid < 32) {
    #pragma unroll
    for (int c4 = 0; c4 < 8; ++c4) {
      float4 t = *reinterpret_cast<const float4*>(&U12s[tid][c4 * 4]);
      *reinterpret_cast<float4*>(A + (size_t)(k0 + tid) * NN + k0 + 32 + c4 * 4) = t;
    }
  }
  // rank-32 update of rows >= k0+32: preg -= L21 * U12  (U rows shared across s)
  #pragma unroll
  for (int l4 = 0; l4 < 8; ++l4) {
    float4 Lv[4];
    #pragma unroll
    for (int s = 0; s < 4; ++s) {
      const int i = k0 + tid + s * 256;
      const bool act = (i < NN) && (i >= k0 + 32);
      if (act) Lv[s] = *reinterpret_cast<const float4*>(A + (size_t)i * NN + k0 + l4 * 4);
      else     Lv[s] = {0.f, 0.f, 0.f, 0.f};
    }
    #pragma unroll
    for (int q = 0; q < 4; ++q) {
      const int l = l4 * 4 + q;
      float Ur[32];
      #pragma unroll
      for (int c4 = 0; c4 < 8; ++c4) {
        float4 uv = *reinterpret_cast<const float4*>(&U12s[l][c4 * 4]);
        Ur[c4 * 4 + 0] = uv.x; Ur[c4 * 4 + 1] = uv.y;
        Ur[c4 * 4 + 2] = uv.z; Ur[c4 * 4 + 3] = uv.w;
      }
      #pragma unroll
      for (int s = 0; s < 4; ++s) {
        const float coef = (q == 0) ? Lv[s].x : (q == 1) ? Lv[s].y
                         : (q == 2) ? Lv[s].z : Lv[s].w;
        #pragma unroll
        for (int c = 0; c < 32; ++c) preg[s][c] -= coef * Ur[c];
      }
    }
  }
  __syncthreads();

  // ---- Phase C: factor right 32 columns ----
  lu_sub32(preg, A, k0, 32, tid, lane, wid, lsum, urow, swapA, redv, redi, &s_piv, sperm);

  if (tid == 0) {
    if (p == 0) logacc[mat] = lsum;
    else        logacc[mat] += lsum;
  }

  // ---- perm lists for trailing-column kernels ----
  __syncthreads();
  if (tid == 0) s_cnt = 0;
  __syncthreads();
  if (tid < 64) prm[PRM_PS + mat * 64 + tid] = sperm[k0 + tid];
  for (int i = k0 + 64 + tid; i < 1024; i += 256) {
    if (sperm[i] != i) {
      int sl = atomicAdd(&s_cnt, 1);
      prm[PRM_TD + mat * 64 + sl] = i;
      prm[PRM_TS + mat * 64 + sl] = sperm[i];
    }
  }
  __syncthreads();
  if (tid == 0) prm[PRM_TC + mat] = s_cnt;
}

// ============ perm-gather swap + TRSM (U12 = L11^-1 P A12), width 64 ============
__global__ __launch_bounds__(256, 1) void lu_swaptrsm64_k(float* __restrict__ Alu,
    int p, const int* __restrict__ prm) {
  int mat = blockIdx.y;
  float* A = Alu + (size_t)mat * NN * NN;
  int k0 = p * 64;
  int col = k0 + 64 + blockIdx.x * 256 + threadIdx.x;
  __shared__ float L11[64][65];
  __shared__ int ps[64], td[64], ts[64];
  __shared__ int s_nc;
  for (int t = threadIdx.x; t < 64 * 64; t += 256) {
    int r = t >> 6, c = t & 63;
    L11[r][c] = A[(size_t)(k0 + r) * NN + k0 + c];
  }
  if (threadIdx.x < 64) {
    ps[threadIdx.x] = prm[PRM_PS + mat * 64 + threadIdx.x];
    td[threadIdx.x] = prm[PRM_TD + mat * 64 + threadIdx.x];
    ts[threadIdx.x] = prm[PRM_TS + mat * 64 + threadIdx.x];
  }
  if (threadIdx.x == 0) s_nc = prm[PRM_TC + mat];
  __syncthreads();
  if (col >= NN) return;
  const int nc = s_nc;

  float u[64], tv[64];
  #pragma unroll
  for (int r = 0; r < 64; ++r) u[r] = A[(size_t)ps[r] * NN + col];
  #pragma unroll
  for (int i = 0; i < 64; ++i) tv[i] = (i < nc) ? A[(size_t)ts[i] * NN + col] : 0.0f;
  #pragma unroll
  for (int i = 0; i < 64; ++i) if (i < nc) A[(size_t)td[i] * NN + col] = tv[i];
  #pragma unroll
  for (int l = 0; l < 64; ++l) {
    float ul = u[l];
    #pragma unroll
    for (int r = l + 1; r < 64; ++r) u[r] -= L11[r][l] * ul;
  }
  #pragma unroll
  for (int r = 0; r < 64; ++r) A[(size_t)(k0 + r) * NN + col] = u[r];
}

// ============ Schur update: A22 -= L21 @ U12 (128x128 tile, K=64) ============
__global__ __launch_bounds__(256) void lu_gemm64_k(float* __restrict__ Alu, int p) {
  int mat = blockIdx.z;
  float* A = Alu + (size_t)mat * NN * NN;
  int k0 = p * 64;
  int base = k0 + 64;
  int r0 = base + blockIdx.y * 128, c0 = base + blockIdx.x * 128;
  __shared__ float Ls[128][36];
  __shared__ float Us[32][132];
  int tid = threadIdx.x, tx = tid & 15, ty = tid >> 4;
  float acc[8][8] = {};
  for (int kk = 0; kk < 64; kk += 32) {
    for (int t = tid; t < 1024; t += 256) {
      int r = t >> 3, cc4 = (t & 7) * 4;
      float4 v = {0.f, 0.f, 0.f, 0.f};
      if (r0 + r < NN)
        v = *reinterpret_cast<const float4*>(A + (size_t)(r0 + r) * NN + k0 + kk + cc4);
      *reinterpret_cast<float4*>(&Ls[r][cc4]) = v;
    }
    for (int t = tid; t < 1024; t += 256) {
      int r = t >> 5, cc4 = (t & 31) * 4;
      float4 v = {0.f, 0.f, 0.f, 0.f};
      if (c0 + cc4 < NN)
        v = *reinterpret_cast<const float4*>(A + (size_t)(k0 + kk + r) * NN + c0 + cc4);
      *reinterpret_cast<float4*>(&Us[r][cc4]) = v;
    }
    __syncthreads();
    #pragma unroll 8
    for (int l = 0; l < 32; ++l) {
      float a[8], bv[8];
      #pragma unroll
      for (int q = 0; q < 4; ++q) {
        a[q]     = Ls[ty * 4 + q][l];
        a[q + 4] = Ls[64 + ty * 4 + q][l];
      }
      #pragma unroll
      for (int r = 0; r < 4; ++r) {
        bv[r]     = Us[l][tx * 4 + r];
        bv[r + 4] = Us[l][64 + tx * 4 + r];
      }
      #pragma unroll
      for (int q = 0; q < 8; ++q)
        #pragma unroll
        for (int r = 0; r < 8; ++r) acc[q][r] += a[q] * bv[r];
    }
    __syncthreads();
  }
  #pragma unroll
  for (int q = 0; q < 8; ++q) {
    int rr = r0 + ((q < 4) ? ty * 4 + q : 64 + ty * 4 + q - 4);
    if (rr < NN) {
      #pragma unroll
      for (int r = 0; r < 8; ++r) {
        int cc = c0 + ((r < 4) ? tx * 4 + r : 64 + tx * 4 + r - 4);
        if (cc < NN) A[(size_t)rr * NN + cc] -= acc[q][r];
      }
    }
  }
}

// ============ thin GEMV: C=4 path ============
__global__ __launch_bounds__(256) void gemv4_k(const float* __restrict__ Gp,
    const float* __restrict__ V, const float* __restrict__ deg,
    const float* __restrict__ cs, float* __restrict__ O, int mode) {
  int wid = threadIdx.x >> 6, lane = threadIdx.x & 63;
  int row = blockIdx.x * 4 + wid;
  int b = row >> 10, i = row & 1023;
  const float* Gr = Gp + (size_t)b * NN * NN + (size_t)i * NN;
  const float* Vb = V + (size_t)b * NN * 4;
  float a0 = 0.f, a1 = 0.f, a2 = 0.f, a3 = 0.f;
  for (int k = lane; k < NN; k += 64) {
    float g = Gr[k];
    float4 v = *reinterpret_cast<const float4*>(Vb + (size_t)k * 4);
    a0 += g * v.x; a1 += g * v.y; a2 += g * v.z; a3 += g * v.w;
  }
  #pragma unroll
  for (int o = 32; o; o >>= 1) {
    a0 += __shfl_down(a0, o, 64); a1 += __shfl_down(a1, o, 64);
    a2 += __shfl_down(a2, o, 64); a3 += __shfl_down(a3, o, 64);
  }
  if (lane == 0) {
    float4 v = *reinterpret_cast<const float4*>(Vb + (size_t)i * 4);
    float dg = deg[row];
    float r0 = dg * v.x - a0, r1 = dg * v.y - a1;
    float r2 = dg * v.z - a2, r3 = dg * v.w - a3;
    if (mode) {
      r0 = 2.f * r0 + v.x + cs[b * 4 + 0];
      r1 = 2.f * r1 + v.y + cs[b * 4 + 1];
      r2 = 2.f * r2 + v.z + cs[b * 4 + 2];
      r3 = 2.f * r3 + v.w + cs[b * 4 + 3];
    }
    float4 o4 = {r0, r1, r2, r3};
    *reinterpret_cast<float4*>(O + (size_t)row * 4) = o4;
  }
}

// ============ L-apply GEMM (C=256): O = deg*V - Gp@V [m0]; 2*that + V + cs [m1] ============
__global__ __launch_bounds__(256) void lgemm2_k(const float* __restrict__ Gp,
    const float* __restrict__ V, const float* __restrict__ deg,
    const float* __restrict__ cs, float* __restrict__ O, int mode) {
  int b = blockIdx.y;
  int i0 = blockIdx.x * 16;
  const float* G = Gp + (size_t)b * NN * NN;
  const float* Vb = V + (size_t)b * NN * CC;
  __shared__ float Gs[16][36];
  __shared__ float Vs[32][256];
  int tid = threadIdx.x;
  int c4 = (tid & 63) * 4, rg = tid >> 6;
  float acc[4][4] = {};
  for (int kk = 0; kk < NN; kk += 32) {
    if (tid < 128) {
      int r = tid >> 3, cc4 = (tid & 7) * 4;
      float4 g = *reinterpret_cast<const float4*>(G + (size_t)(i0 + r) * NN + kk + cc4);
      *reinterpret_cast<float4*>(&Gs[r][cc4]) = g;
    }
    #pragma unroll
    for (int it = 0; it < 8; ++it) {
      int idx = tid + it * 256;
      int r = idx >> 6, vc4 = (idx & 63) * 4;
      float4 v = *reinterpret_cast<const float4*>(Vb + (size_t)(kk + r) * CC + vc4);
      *reinterpret_cast<float4*>(&Vs[r][vc4]) = v;
    }
    __syncthreads();
    #pragma unroll
    for (int k4 = 0; k4 < 8; ++k4) {
      float4 g0 = *reinterpret_cast<const float4*>(&Gs[rg * 4 + 0][k4 * 4]);
      float4 g1 = *reinterpret_cast<const float4*>(&Gs[rg * 4 + 1][k4 * 4]);
      float4 g2 = *reinterpret_cast<const float4*>(&Gs[rg * 4 + 2][k4 * 4]);
      float4 g3 = *reinterpret_cast<const float4*>(&Gs[rg * 4 + 3][k4 * 4]);
      float4 v0 = *reinterpret_cast<const float4*>(&Vs[k4 * 4 + 0][c4]);
      float4 v1 = *reinterpret_cast<const float4*>(&Vs[k4 * 4 + 1][c4]);
      float4 v2 = *reinterpret_cast<const float4*>(&Vs[k4 * 4 + 2][c4]);
      float4 v3 = *reinterpret_cast<const float4*>(&Vs[k4 * 4 + 3][c4]);
      float ga[4][4] = {{g0.x, g0.y, g0.z, g0.w}, {g1.x, g1.y, g1.z, g1.w},
                        {g2.x, g2.y, g2.z, g2.w}, {g3.x, g3.y, g3.z, g3.w}};
      float va[4][4] = {{v0.x, v0.y, v0.z, v0.w}, {v1.x, v1.y, v1.z, v1.w},
                        {v2.x, v2.y, v2.z, v2.w}, {v3.x, v3.y, v3.z, v3.w}};
      #pragma unroll
      for (int kq = 0; kq < 4; ++kq)
        #pragma unroll
        for (int q = 0; q < 4; ++q)
          #pragma unroll
          for (int r = 0; r < 4; ++r) acc[q][r] += ga[q][kq] * va[kq][r];
    }
    __syncthreads();
  }
  #pragma unroll
  for (int q = 0; q < 4; ++q) {
    int i = i0 + rg * 4 + q;
    float dg = deg[b * NN + i];
    float4 vv = *reinterpret_cast<const float4*>(Vb + (size_t)i * CC + c4);
    float vo[4] = {vv.x, vv.y, vv.z, vv.w};
    float res[4];
    #pragma unroll
    for (int r = 0; r < 4; ++r) res[r] = dg * vo[r] - acc[q][r];
    if (mode) {
      float4 cv = *reinterpret_cast<const float4*>(cs + b * CC + c4);
      float co[4] = {cv.x, cv.y, cv.z, cv.w};
      #pragma unroll
      for (int r = 0; r < 4; ++r) res[r] = 2.f * res[r] + vo[r] + co[r];
    }
    float4 o4 = {res[0], res[1], res[2], res[3]};
    *reinterpret_cast<float4*>(O + ((size_t)b * NN + i) * CC + c4) = o4;
  }
}

// ============ conv1d: [B,N,4] -> [B,N,256], K=5, pad 2 ============
__global__ __launch_bounds__(256) void conv_k(const float* __restrict__ xp,
    const float* __restrict__ w, const float* __restrict__ bias,
    float* __restrict__ x1out) {
  int bn = blockIdx.x;
  int b = bn >> 10, n = bn & 1023;
  int co = threadIdx.x;
  __shared__ float xs[5][4];
  if (threadIdx.x < 20) {
    int k = threadIdx.x >> 2, ci = threadIdx.x & 3;
    int n2 = n + k - 2;
    xs[k][ci] = (n2 >= 0 && n2 < NN) ? xp[((size_t)b * NN + n2) * 4 + ci] : 0.0f;
  }
  __syncthreads();
  const float* wp = w + co * 20;
  float acc = bias[co];
  #pragma unroll
  for (int ci = 0; ci < 4; ++ci)
    #pragma unroll
    for (int k = 0; k < 5; ++k) acc += wp[ci * 5 + k] * xs[k][ci];
  x1out[((size_t)b * NN + n) * CC + co] = acc;
}

// ============ Wasserstein: bitonic sort 1024 per (b,c), sum |s1-s2| ============
__global__ __launch_bounds__(256) void wass_k(const float* __restrict__ x1,
    const float* __restrict__ x2, float* __restrict__ part) {
  int bc = blockIdx.x;
  int b = bc >> 8, c = bc & 255;
  __shared__ float s1[1024];
  __shared__ float s2[1024];
  __shared__ float red[256];
  int t = threadIdx.x;
  for (int q = 0; q < 4; ++q) {
    int n = t + q * 256;
    s1[n] = x1[((size_t)b * NN + n) * CC + c];
    s2[n] = x2[((size_t)b * NN + n) * CC + c];
  }
  __syncthreads();
  for (int k = 2; k <= 1024; k <<= 1) {
    for (int j = k >> 1; j > 0; j >>= 1) {
      #pragma unroll
      for (int q = 0; q < 2; ++q) {
        int idx = t + q * 256;
        int i = ((idx & ~(j - 1)) << 1) | (idx & (j - 1));
        int l = i | j;
        bool up = ((i & k) == 0);
        float a = s1[i], bvv = s1[l];
        if ((a > bvv) == up) { s1[i] = bvv; s1[l] = a; }
        a = s2[i]; bvv = s2[l];
        if ((a > bvv) == up) { s2[i] = bvv; s2[l] = a; }
      }
      __syncthreads();
    }
  }
  float s = 0.f;
  for (int q = 0; q < 4; ++q) {
    int n = t + q * 256;
    s += fabsf(s1[n] - s2[n]);
  }
  red[t] = s;
  __syncthreads();
  for (int o = 128; o; o >>= 1) {
    if (t < o) red[t] += red[t + o];
    __syncthreads();
  }
  if (!t) part[bc] = red[0];
}

// ============ finalize losses ============
__global__ __launch_bounds__(256) void finalize_k(const float* __restrict__ logacc,
    const float* __restrict__ part, float* __restrict__ out) {
  int t = threadIdx.x;
  __shared__ double red[256];
  double s = 0.0;
  for (int i = t; i < 2048; i += 256) s += (double)part[i];
  red[t] = s;
  __syncthreads();
  for (int o = 128; o; o >>= 1) {
    if (t < o) red[t] += red[t + o];
    __syncthreads();
  }
  if (!t) {
    double l1 = 0.0, l2 = 0.0;
    for (int i = 0; i < 8; ++i) { l1 += (double)logacc[i]; l2 += (double)logacc[8 + i]; }
    out[OUT_L + 0] = (float)(-l1 / 8.0);
    out[OUT_L + 1] = (float)(-l2 / 8.0);
    out[OUT_L + 2] = (float)(red[0] / 2097152.0);
  }
}

extern "C" void kernel_launch(void* const* d_in, const int* in_sizes, int n_in,
                              void* d_out, int out_size, void* d_ws, size_t ws_size,
                              hipStream_t stream) {
  (void)in_sizes; (void)n_in; (void)out_size; (void)ws_size;
  const float* G1 = (const float*)d_in[0];
  const float* G2 = (const float*)d_in[1];
  const float* R1 = (const float*)d_in[2];
  const float* R2 = (const float*)d_in[3];
  const float* U1 = (const float*)d_in[7];
  const float* U2 = (const float*)d_in[8];
  const float* CW = (const float*)d_in[9];
  const float* CB = (const float*)d_in[10];
  const float* BG = (const float*)d_in[11];
  const float* BBt = (const float*)d_in[12];
  float* out = (float*)d_out;
  float* ws = (float*)d_ws;

  float* Alu    = ws + OFF_ALU;
  float* logacc = ws + OFF_LOGACC;
  int*   prm    = (int*)(ws + OFF_PIV);
  float* deg    = ws + OFF_DEG;
  float* R2n    = ws + OFF_R2N;
  float* LR2    = ws + OFF_LR2;
  float* LR1    = ws + OFF_LR1;
  float* X1P    = ws + OFF_X1P;
  float* CS1    = ws + OFF_CS1;
  float* CS2    = ws + OFF_CS2;
  float* BNP    = ws + OFF_BNP;
  float* BNS    = ws + OFF_BNS;
  float* WSP    = ws + OFF_WSP;

  pool_pair_k<<<dim3(136, 1, 16), 256, 0, stream>>>(G1, G2, U1, U2, out, Alu);
  deg_k<<<4096, 256, 0, stream>>>(out, deg);

  bn_partial_k<<<64, 256, 0, stream>>>(R2, BNP);
  bn_final_k<<<1, 256, 0, stream>>>(BNP, BG, BBt, BNS);
  bn_apply_k<<<8192, 256, 0, stream>>>(R2, BNS, R2n);
  colsum2_k<<<8, 256, 0, stream>>>(R2n, CS2);
  colsum1_k<<<1, 64, 0, stream>>>(R1, CS1);

  // x1 path
  gemv4_k<<<2048, 256, 0, stream>>>(out, R1, deg, CS1, LR1, 0);
  gemv4_k<<<2048, 256, 0, stream>>>(out, LR1, deg, CS1, X1P, 1);
  conv_k<<<8192, 256, 0, stream>>>(X1P, CW, CB, out + OUT_X1);

  // x2 path
  lgemm2_k<<<dim3(64, 8), 256, 0, stream>>>(out + OUT_G2P, R2n, deg + 8192, CS2, LR2, 0);
  lgemm2_k<<<dim3(64, 8), 256, 0, stream>>>(out + OUT_G2P, LR2, deg + 8192, CS2, out + OUT_X2, 1);

  // blocked LU (NB=64, two fused 32-col register sub-panels) on A = Gp + 1e-3 I
  for (int p = 0; p < NN / 64; ++p) {
    lu_panel64_k<<<16, 256, 0, stream>>>(Alu, p, logacc, prm);
    int rem = NN - (p + 1) * 64;
    if (rem > 0) {
      lu_swaptrsm64_k<<<dim3((rem + 255) / 256, 16), 256, 0, stream>>>(Alu, p, prm);
      int mt = (rem + 127) / 128;
      lu_gemm64_k<<<dim3(mt, mt, 16), 256, 0, stream>>>(Alu, p);
    }
  }

  wass_k<<<2048, 256, 0, stream>>>(out + OUT_X1, out + OUT_X2, WSP);
  finalize_k<<<1, 256, 0, stream>>>(logacc, WSP, out);
}

// Round 4
// 3639.965 us; speedup vs baseline: 1.6202x; 1.1906x over previous
//
#include <hip/hip_runtime.h>

#define NN 1024
#define CC 256

// ---- output offsets (floats) ----
constexpr size_t OUT_G2P = 8ull * NN * NN;
constexpr size_t OUT_X1  = 16ull * NN * NN;
constexpr size_t OUT_X2  = OUT_X1 + 8ull * NN * CC;
constexpr size_t OUT_L   = OUT_X2 + 8ull * NN * CC;

// ---- workspace offsets (floats) ----
constexpr size_t OFF_ALU    = 0;                        // 16M floats
constexpr size_t OFF_LOGACC = 16ull * NN * NN;          // 256
constexpr size_t OFF_PIV    = OFF_LOGACC + 256;         // 4096 ints (perm lists)
constexpr size_t OFF_DEG    = OFF_PIV + 4096;           // 16384
constexpr size_t OFF_R2N    = OFF_DEG + 16384;          // 2097152
constexpr size_t OFF_LR2    = OFF_R2N + 2097152;        // 2097152
constexpr size_t OFF_LR1    = OFF_LR2 + 2097152;        // 32768
constexpr size_t OFF_X1P    = OFF_LR1 + 32768;          // 32768
constexpr size_t OFF_CS1    = OFF_X1P + 32768;          // 256
constexpr size_t OFF_CS2    = OFF_CS1 + 256;            // 2048
constexpr size_t OFF_BNP    = OFF_CS2 + 2048;           // 32768
constexpr size_t OFF_BNS    = OFF_BNP + 32768;          // 1024
constexpr size_t OFF_WSP    = OFF_BNS + 1024;           // 2048

// perm-list layout inside OFF_PIV (ints): PS[16][64], TD[16][64], TS[16][64], TC[16]
#define PRM_PS 0
#define PRM_TD 1024
#define PRM_TS 2048
#define PRM_TC 3072

// ============ pooling (pair tiles): Gp = 0.5*(W + W^T), A = Gp + 1e-3 I ============
__global__ __launch_bounds__(256) void pool_pair_k(const float* __restrict__ G1,
    const float* __restrict__ G2, const float* __restrict__ U1,
    const float* __restrict__ U2, float* __restrict__ out, float* __restrict__ Alu) {
  int mat = blockIdx.z, g = mat >> 3, b = mat & 7;
  const float* G = (g ? G2 : G1) + (size_t)b * NN * NN;
  const float* U = g ? U2 : U1;
  float* Gp = out + (size_t)mat * NN * NN;
  float* A  = Alu + (size_t)mat * NN * NN;

  int pid = blockIdx.x;
  int ti = 0, rem = pid;
  while (rem >= 16 - ti) { rem -= 16 - ti; ++ti; }
  int tj = ti + rem;

  int tc = threadIdx.x & 63, tr = threadIdx.x >> 6;
  __shared__ float Wa[64][65];
  __shared__ float Wb[64][65];
  #pragma unroll
  for (int s = 0; s < 16; ++s) {
    int r = s * 4 + tr;
    size_t ia = (size_t)(ti * 64 + r) * NN + tj * 64 + tc;
    size_t ib = (size_t)(tj * 64 + r) * NN + ti * 64 + tc;
    Wa[r][tc] = U[ia] * G[ia];
    Wb[r][tc] = U[ib] * G[ib];
  }
  __syncthreads();
  #pragma unroll
  for (int s = 0; s < 16; ++s) {
    int r = s * 4 + tr;
    float o1 = 0.5f * (Wa[r][tc] + Wb[tc][r]);
    size_t idx1 = (size_t)(ti * 64 + r) * NN + tj * 64 + tc;
    Gp[idx1] = o1;
    A[idx1] = o1 + ((ti == tj && r == tc) ? 1e-3f : 0.0f);
    if (ti != tj) {
      float o2 = 0.5f * (Wb[r][tc] + Wa[tc][r]);
      size_t idx2 = (size_t)(tj * 64 + r) * NN + ti * 64 + tc;
      Gp[idx2] = o2;
      A[idx2] = o2;
    }
  }
}

// ============ deg[b,i] = sum_j Gp[b,i,j] ============
__global__ __launch_bounds__(256) void deg_k(const float* __restrict__ out,
                                             float* __restrict__ deg) {
  int wid = threadIdx.x >> 6, lane = threadIdx.x & 63;
  int row = blockIdx.x * 4 + wid;
  const float* Gp = out + (size_t)row * NN;
  float s = 0.f;
  for (int k = lane; k < NN; k += 64) s += Gp[k];
  #pragma unroll
  for (int o = 32; o; o >>= 1) s += __shfl_down(s, o, 64);
  if (!lane) deg[row] = s;
}

// ============ batchnorm ============
__global__ __launch_bounds__(256) void bn_partial_k(const float* __restrict__ R2,
                                                    float* __restrict__ part) {
  int w = blockIdx.x, c = threadIdx.x;
  float s = 0.f, s2 = 0.f;
  for (int r = w * 128; r < (w + 1) * 128; ++r) {
    float x = R2[(size_t)r * CC + c];
    s += x; s2 += x * x;
  }
  part[w * 512 + c] = s;
  part[w * 512 + 256 + c] = s2;
}

__global__ __launch_bounds__(256) void bn_final_k(const float* __restrict__ part,
    const float* __restrict__ g, const float* __restrict__ bt, float* __restrict__ stats) {
  int c = threadIdx.x;
  float s = 0.f, s2 = 0.f;
  for (int w = 0; w < 64; ++w) { s += part[w * 512 + c]; s2 += part[w * 512 + 256 + c]; }
  float mu = s / 8192.0f, var = s2 / 8192.0f - mu * mu;
  stats[c] = mu;
  stats[256 + c] = rsqrtf(var + 1e-5f) * g[c];
  stats[512 + c] = bt[c];
}

__global__ __launch_bounds__(256) void bn_apply_k(const float* __restrict__ R2,
    const float* __restrict__ stats, float* __restrict__ R2n) {
  int c = threadIdx.x;
  size_t i = (size_t)blockIdx.x * CC + c;
  R2n[i] = (R2[i] - stats[c]) * stats[256 + c] + stats[512 + c];
}

// ============ column sums ============
__global__ __launch_bounds__(256) void colsum2_k(const float* __restrict__ R2n,
                                                 float* __restrict__ cs2) {
  int b = blockIdx.x, c = threadIdx.x;
  float s = 0.f;
  for (int n = 0; n < NN; ++n) s += R2n[((size_t)b * NN + n) * CC + c];
  cs2[b * CC + c] = s;
}

__global__ __launch_bounds__(64) void colsum1_k(const float* __restrict__ R1,
                                                float* __restrict__ cs1) {
  int t = threadIdx.x;
  if (t >= 32) return;
  int b = t >> 2, c = t & 3;
  float s = 0.f;
  for (int n = 0; n < NN; ++n) s += R1[((size_t)b * NN + n) * 4 + c];
  cs1[b * 4 + c] = s;
}

// ============ 32-col sub-panel, ONE ROW PER THREAD (1024 thr, no spill) ============
__device__ __forceinline__ void lu_sub32_1r(float (&preg)[32], float* __restrict__ A,
    int k0, int off, int tid, int lane, int wid, float& lsum,
    float* urow, float* swapA, float* redv, int* redi, int* s_piv, int* sperm) {
  #pragma unroll 1
  for (int j = 0; j < 32; ++j) {
    const int rb = k0 + off + j;
    // pivot argmax over rows >= rb (thread tid owns row tid)
    float bv = (tid >= rb) ? fabsf(preg[0]) : -1.0f;
    int br = tid;
    #pragma unroll
    for (int o = 32; o; o >>= 1) {
      const float ov = __shfl_down(bv, o, 64);
      const int   oi = __shfl_down(br, o, 64);
      if (ov > bv) { bv = ov; br = oi; }
    }
    if (lane == 0) { redv[wid] = bv; redi[wid] = br; }
    __syncthreads();                              // B1
    if (tid == 0) {
      float fv = redv[0]; int fi = redi[0];
      #pragma unroll
      for (int w = 1; w < 16; ++w)
        if (redv[w] > fv) { fv = redv[w]; fi = redi[w]; }
      *s_piv = fi;
      lsum += logf(fmaxf(fv, 1e-37f));
      int t = sperm[rb]; sperm[rb] = sperm[fi]; sperm[fi] = t;
    }
    __syncthreads();                              // B2
    const int pr = *s_piv;

    // swap already-streamed history (global cols k0 .. k0+off+j-1)
    const int hist = off + j;
    if (tid < hist && pr != rb) {
      size_t a1 = (size_t)rb * NN + k0 + tid;
      size_t a2 = (size_t)pr * NN + k0 + tid;
      float t1 = A[a1], t2 = A[a2];
      A[a1] = t2; A[a2] = t1;
    }

    // register row swap via LDS (thread id == row id)
    if (tid == rb) {
      #pragma unroll
      for (int c = 0; c < 32; ++c) swapA[c] = preg[c];
    }
    if (tid == pr) {
      #pragma unroll
      for (int c = 0; c < 32; ++c) urow[c] = preg[c];
    }
    __syncthreads();                              // B3
    if (tid == pr && pr != rb) {
      #pragma unroll
      for (int c = 0; c < 32; ++c) preg[c] = swapA[c];
    }

    // stream U row (cols rb .. k0+off+31)
    const int W = 32 - j;
    if (tid < W) A[(size_t)rb * NN + rb + tid] = urow[tid];

    // rank-1 update + column shift; urow read as LDS broadcast
    const float pv = urow[0];
    const float pvs = (fabsf(pv) < 1e-37f) ? copysignf(1e-37f, pv) : pv;
    const float ipv = 1.0f / pvs;
    const bool act = (tid > rb);
    const float lm = act ? preg[0] * ipv : 0.0f;
    if (act) A[(size_t)tid * NN + rb] = lm;
    #pragma unroll
    for (int c = 1; c < 32; ++c) preg[c - 1] = preg[c] - lm * urow[c];
  }
}

// ============ LU panel NB=64 = two fused 32-col sub-panels, 1024 threads ============
__global__ __launch_bounds__(1024, 1) void lu_panel64_k(float* __restrict__ Alu, int p,
    float* __restrict__ logacc, int* __restrict__ prm) {
  const int mat = blockIdx.x;
  float* A = Alu + (size_t)mat * NN * NN;
  const int k0 = p * 64;
  const int tid = threadIdx.x;
  const int lane = tid & 63, wid = tid >> 6;

  __shared__ __align__(16) float urow[32];
  __shared__ __align__(16) float swapA[32];
  __shared__ __align__(16) float U12s[32][33];
  __shared__ __align__(16) float L11s[32][33];
  __shared__ float redv[16];
  __shared__ int   redi[16];
  __shared__ int   s_piv;
  __shared__ int   sperm[1024];
  __shared__ int   s_cnt;

  sperm[tid] = tid;
  __syncthreads();

  float preg[32];
  float lsum = 0.0f;

  // ---- Phase A: load left 32 cols (row tid) + factor ----
  if (tid >= k0) {
    const float4* Ar = reinterpret_cast<const float4*>(A + (size_t)tid * NN + k0);
    #pragma unroll
    for (int c4 = 0; c4 < 8; ++c4) {
      float4 v = Ar[c4];
      preg[c4 * 4 + 0] = v.x; preg[c4 * 4 + 1] = v.y;
      preg[c4 * 4 + 2] = v.z; preg[c4 * 4 + 3] = v.w;
    }
  } else {
    #pragma unroll
    for (int c = 0; c < 32; ++c) preg[c] = 0.0f;
  }

  lu_sub32_1r(preg, A, k0, 0, tid, lane, wid, lsum, urow, swapA, redv, redi, &s_piv, sperm);

  // ---- Phase B: gather right strip (P applied), TRSM top, rank-32 update ----
  __syncthreads();
  if (tid >= k0) {
    const int src = sperm[tid];
    const float4* Ar = reinterpret_cast<const float4*>(A + (size_t)src * NN + k0 + 32);
    #pragma unroll
    for (int c4 = 0; c4 < 8; ++c4) {
      float4 v = Ar[c4];
      preg[c4 * 4 + 0] = v.x; preg[c4 * 4 + 1] = v.y;
      preg[c4 * 4 + 2] = v.z; preg[c4 * 4 + 3] = v.w;
    }
  }
  // strip-top rows -> U12s
  if (tid >= k0 && tid < k0 + 32) {
    const int r = tid - k0;
    #pragma unroll
    for (int c = 0; c < 32; ++c) U12s[r][c] = preg[c];
  }
  // L11 -> LDS (1024 threads cover 32x32)
  {
    const int r = tid >> 5, c = tid & 31;
    L11s[r][c] = A[(size_t)(k0 + r) * NN + k0 + c];
  }
  __syncthreads();
  // TRSM: thread c solves column c of the 32x32 top block
  if (tid < 32) {
    float u[32];
    #pragma unroll
    for (int r = 0; r < 32; ++r) u[r] = U12s[r][tid];
    #pragma unroll
    for (int l = 0; l < 32; ++l) {
      const float ul = u[l];
      #pragma unroll
      for (int r = 0; r < 32; ++r)
        if (r > l) u[r] -= L11s[r][l] * ul;
    }
    #pragma unroll
    for (int r = 0; r < 32; ++r) U12s[r][tid] = u[r];
  }
  __syncthreads();
  // write U12 to global
  {
    const int r = tid >> 5, c = tid & 31;
    A[(size_t)(k0 + r) * NN + k0 + 32 + c] = U12s[r][c];
  }
  // rows in strip-top: preg holds solved U12 row
  if (tid >= k0 && tid < k0 + 32) {
    const int r = tid - k0;
    #pragma unroll
    for (int c = 0; c < 32; ++c) preg[c] = U12s[r][c];
  }
  // rank-32 update for rows >= k0+32: preg -= L21row * U12
  if (tid >= k0 + 32) {
    const float4* Lr = reinterpret_cast<const float4*>(A + (size_t)tid * NN + k0);
    #pragma unroll
    for (int l4 = 0; l4 < 8; ++l4) {
      float4 lv = Lr[l4];
      #pragma unroll
      for (int q = 0; q < 4; ++q) {
        const int l = l4 * 4 + q;
        const float coef = (q == 0) ? lv.x : (q == 1) ? lv.y : (q == 2) ? lv.z : lv.w;
        #pragma unroll
        for (int c = 0; c < 32; ++c) preg[c] -= coef * U12s[l][c];
      }
    }
  }
  __syncthreads();

  // ---- Phase C: factor right 32 columns ----
  lu_sub32_1r(preg, A, k0, 32, tid, lane, wid, lsum, urow, swapA, redv, redi, &s_piv, sperm);

  if (tid == 0) {
    if (p == 0) logacc[mat] = lsum;
    else        logacc[mat] += lsum;
  }

  // ---- perm lists for trailing-column kernels ----
  __syncthreads();
  if (tid == 0) s_cnt = 0;
  __syncthreads();
  if (tid < 64) prm[PRM_PS + mat * 64 + tid] = sperm[k0 + tid];
  if (tid >= k0 + 64 && sperm[tid] != tid) {
    int sl = atomicAdd(&s_cnt, 1);
    prm[PRM_TD + mat * 64 + sl] = tid;
    prm[PRM_TS + mat * 64 + sl] = sperm[tid];
  }
  __syncthreads();
  if (tid == 0) prm[PRM_TC + mat] = s_cnt;
}

// ============ perm-gather swap + TRSM (U12 = L11^-1 P A12), width 64 ============
__global__ __launch_bounds__(256, 1) void lu_swaptrsm64_k(float* __restrict__ Alu,
    int p, const int* __restrict__ prm) {
  int mat = blockIdx.y;
  float* A = Alu + (size_t)mat * NN * NN;
  int k0 = p * 64;
  int col = k0 + 64 + blockIdx.x * 256 + threadIdx.x;
  __shared__ float L11[64][65];
  __shared__ int ps[64], td[64], ts[64];
  __shared__ int s_nc;
  for (int t = threadIdx.x; t < 64 * 64; t += 256) {
    int r = t >> 6, c = t & 63;
    L11[r][c] = A[(size_t)(k0 + r) * NN + k0 + c];
  }
  if (threadIdx.x < 64) {
    ps[threadIdx.x] = prm[PRM_PS + mat * 64 + threadIdx.x];
    td[threadIdx.x] = prm[PRM_TD + mat * 64 + threadIdx.x];
    ts[threadIdx.x] = prm[PRM_TS + mat * 64 + threadIdx.x];
  }
  if (threadIdx.x == 0) s_nc = prm[PRM_TC + mat];
  __syncthreads();
  if (col >= NN) return;
  const int nc = s_nc;

  float u[64], tv[64];
  #pragma unroll
  for (int r = 0; r < 64; ++r) u[r] = A[(size_t)ps[r] * NN + col];
  #pragma unroll
  for (int i = 0; i < 64; ++i) tv[i] = (i < nc) ? A[(size_t)ts[i] * NN + col] : 0.0f;
  #pragma unroll
  for (int i = 0; i < 64; ++i) if (i < nc) A[(size_t)td[i] * NN + col] = tv[i];
  #pragma unroll
  for (int l = 0; l < 64; ++l) {
    float ul = u[l];
    #pragma unroll
    for (int r = l + 1; r < 64; ++r) u[r] -= L11[r][l] * ul;
  }
  #pragma unroll
  for (int r = 0; r < 64; ++r) A[(size_t)(k0 + r) * NN + col] = u[r];
}

// ============ Schur update: A22 -= L21 @ U12 (128x128 tile, K=64) ============
__global__ __launch_bounds__(256) void lu_gemm64_k(float* __restrict__ Alu, int p) {
  int mat = blockIdx.z;
  float* A = Alu + (size_t)mat * NN * NN;
  int k0 = p * 64;
  int base = k0 + 64;
  int r0 = base + blockIdx.y * 128, c0 = base + blockIdx.x * 128;
  __shared__ float Ls[128][36];
  __shared__ float Us[32][132];
  int tid = threadIdx.x, tx = tid & 15, ty = tid >> 4;
  float acc[8][8] = {};
  for (int kk = 0; kk < 64; kk += 32) {
    for (int t = tid; t < 1024; t += 256) {
      int r = t >> 3, cc4 = (t & 7) * 4;
      float4 v = {0.f, 0.f, 0.f, 0.f};
      if (r0 + r < NN)
        v = *reinterpret_cast<const float4*>(A + (size_t)(r0 + r) * NN + k0 + kk + cc4);
      *reinterpret_cast<float4*>(&Ls[r][cc4]) = v;
    }
    for (int t = tid; t < 1024; t += 256) {
      int r = t >> 5, cc4 = (t & 31) * 4;
      float4 v = {0.f, 0.f, 0.f, 0.f};
      if (c0 + cc4 < NN)
        v = *reinterpret_cast<const float4*>(A + (size_t)(k0 + kk + r) * NN + c0 + cc4);
      *reinterpret_cast<float4*>(&Us[r][cc4]) = v;
    }
    __syncthreads();
    #pragma unroll 8
    for (int l = 0; l < 32; ++l) {
      float a[8], bv[8];
      #pragma unroll
      for (int q = 0; q < 4; ++q) {
        a[q]     = Ls[ty * 4 + q][l];
        a[q + 4] = Ls[64 + ty * 4 + q][l];
      }
      #pragma unroll
      for (int r = 0; r < 4; ++r) {
        bv[r]     = Us[l][tx * 4 + r];
        bv[r + 4] = Us[l][64 + tx * 4 + r];
      }
      #pragma unroll
      for (int q = 0; q < 8; ++q)
        #pragma unroll
        for (int r = 0; r < 8; ++r) acc[q][r] += a[q] * bv[r];
    }
    __syncthreads();
  }
  #pragma unroll
  for (int q = 0; q < 8; ++q) {
    int rr = r0 + ((q < 4) ? ty * 4 + q : 64 + ty * 4 + q - 4);
    if (rr < NN) {
      #pragma unroll
      for (int r = 0; r < 8; ++r) {
        int cc = c0 + ((r < 4) ? tx * 4 + r : 64 + tx * 4 + r - 4);
        if (cc < NN) A[(size_t)rr * NN + cc] -= acc[q][r];
      }
    }
  }
}

// ============ thin GEMV: C=4 path ============
__global__ __launch_bounds__(256) void gemv4_k(const float* __restrict__ Gp,
    const float* __restrict__ V, const float* __restrict__ deg,
    const float* __restrict__ cs, float* __restrict__ O, int mode) {
  int wid = threadIdx.x >> 6, lane = threadIdx.x & 63;
  int row = blockIdx.x * 4 + wid;
  int b = row >> 10, i = row & 1023;
  const float* Gr = Gp + (size_t)b * NN * NN + (size_t)i * NN;
  const float* Vb = V + (size_t)b * NN * 4;
  float a0 = 0.f, a1 = 0.f, a2 = 0.f, a3 = 0.f;
  for (int k = lane; k < NN; k += 64) {
    float g = Gr[k];
    float4 v = *reinterpret_cast<const float4*>(Vb + (size_t)k * 4);
    a0 += g * v.x; a1 += g * v.y; a2 += g * v.z; a3 += g * v.w;
  }
  #pragma unroll
  for (int o = 32; o; o >>= 1) {
    a0 += __shfl_down(a0, o, 64); a1 += __shfl_down(a1, o, 64);
    a2 += __shfl_down(a2, o, 64); a3 += __shfl_down(a3, o, 64);
  }
  if (lane == 0) {
    float4 v = *reinterpret_cast<const float4*>(Vb + (size_t)i * 4);
    float dg = deg[row];
    float r0 = dg * v.x - a0, r1 = dg * v.y - a1;
    float r2 = dg * v.z - a2, r3 = dg * v.w - a3;
    if (mode) {
      r0 = 2.f * r0 + v.x + cs[b * 4 + 0];
      r1 = 2.f * r1 + v.y + cs[b * 4 + 1];
      r2 = 2.f * r2 + v.z + cs[b * 4 + 2];
      r3 = 2.f * r3 + v.w + cs[b * 4 + 3];
    }
    float4 o4 = {r0, r1, r2, r3};
    *reinterpret_cast<float4*>(O + (size_t)row * 4) = o4;
  }
}

// ============ L-apply GEMM (C=256): O = deg*V - Gp@V [m0]; 2*that + V + cs [m1] ============
__global__ __launch_bounds__(256) void lgemm2_k(const float* __restrict__ Gp,
    const float* __restrict__ V, const float* __restrict__ deg,
    const float* __restrict__ cs, float* __restrict__ O, int mode) {
  int b = blockIdx.y;
  int i0 = blockIdx.x * 16;
  const float* G = Gp + (size_t)b * NN * NN;
  const float* Vb = V + (size_t)b * NN * CC;
  __shared__ float Gs[16][36];
  __shared__ float Vs[32][256];
  int tid = threadIdx.x;
  int c4 = (tid & 63) * 4, rg = tid >> 6;
  float acc[4][4] = {};
  for (int kk = 0; kk < NN; kk += 32) {
    if (tid < 128) {
      int r = tid >> 3, cc4 = (tid & 7) * 4;
      float4 g = *reinterpret_cast<const float4*>(G + (size_t)(i0 + r) * NN + kk + cc4);
      *reinterpret_cast<float4*>(&Gs[r][cc4]) = g;
    }
    #pragma unroll
    for (int it = 0; it < 8; ++it) {
      int idx = tid + it * 256;
      int r = idx >> 6, vc4 = (idx & 63) * 4;
      float4 v = *reinterpret_cast<const float4*>(Vb + (size_t)(kk + r) * CC + vc4);
      *reinterpret_cast<float4*>(&Vs[r][vc4]) = v;
    }
    __syncthreads();
    #pragma unroll
    for (int k4 = 0; k4 < 8; ++k4) {
      float4 g0 = *reinterpret_cast<const float4*>(&Gs[rg * 4 + 0][k4 * 4]);
      float4 g1 = *reinterpret_cast<const float4*>(&Gs[rg * 4 + 1][k4 * 4]);
      float4 g2 = *reinterpret_cast<const float4*>(&Gs[rg * 4 + 2][k4 * 4]);
      float4 g3 = *reinterpret_cast<const float4*>(&Gs[rg * 4 + 3][k4 * 4]);
      float4 v0 = *reinterpret_cast<const float4*>(&Vs[k4 * 4 + 0][c4]);
      float4 v1 = *reinterpret_cast<const float4*>(&Vs[k4 * 4 + 1][c4]);
      float4 v2 = *reinterpret_cast<const float4*>(&Vs[k4 * 4 + 2][c4]);
      float4 v3 = *reinterpret_cast<const float4*>(&Vs[k4 * 4 + 3][c4]);
      float ga[4][4] = {{g0.x, g0.y, g0.z, g0.w}, {g1.x, g1.y, g1.z, g1.w},
                        {g2.x, g2.y, g2.z, g2.w}, {g3.x, g3.y, g3.z, g3.w}};
      float va[4][4] = {{v0.x, v0.y, v0.z, v0.w}, {v1.x, v1.y, v1.z, v1.w},
                        {v2.x, v2.y, v2.z, v2.w}, {v3.x, v3.y, v3.z, v3.w}};
      #pragma unroll
      for (int kq = 0; kq < 4; ++kq)
        #pragma unroll
        for (int q = 0; q < 4; ++q)
          #pragma unroll
          for (int r = 0; r < 4; ++r) acc[q][r] += ga[q][kq] * va[kq][r];
    }
    __syncthreads();
  }
  #pragma unroll
  for (int q = 0; q < 4; ++q) {
    int i = i0 + rg * 4 + q;
    float dg = deg[b * NN + i];
    float4 vv = *reinterpret_cast<const float4*>(Vb + (size_t)i * CC + c4);
    float vo[4] = {vv.x, vv.y, vv.z, vv.w};
    float res[4];
    #pragma unroll
    for (int r = 0; r < 4; ++r) res[r] = dg * vo[r] - acc[q][r];
    if (mode) {
      float4 cv = *reinterpret_cast<const float4*>(cs + b * CC + c4);
      float co[4] = {cv.x, cv.y, cv.z, cv.w};
      #pragma unroll
      for (int r = 0; r < 4; ++r) res[r] = 2.f * res[r] + vo[r] + co[r];
    }
    float4 o4 = {res[0], res[1], res[2], res[3]};
    *reinterpret_cast<float4*>(O + ((size_t)b * NN + i) * CC + c4) = o4;
  }
}

// ============ conv1d: [B,N,4] -> [B,N,256], K=5, pad 2 ============
__global__ __launch_bounds__(256) void conv_k(const float* __restrict__ xp,
    const float* __restrict__ w, const float* __restrict__ bias,
    float* __restrict__ x1out) {
  int bn = blockIdx.x;
  int b = bn >> 10, n = bn & 1023;
  int co = threadIdx.x;
  __shared__ float xs[5][4];
  if (threadIdx.x < 20) {
    int k = threadIdx.x >> 2, ci = threadIdx.x & 3;
    int n2 = n + k - 2;
    xs[k][ci] = (n2 >= 0 && n2 < NN) ? xp[((size_t)b * NN + n2) * 4 + ci] : 0.0f;
  }
  __syncthreads();
  const float* wp = w + co * 20;
  float acc = bias[co];
  #pragma unroll
  for (int ci = 0; ci < 4; ++ci)
    #pragma unroll
    for (int k = 0; k < 5; ++k) acc += wp[ci * 5 + k] * xs[k][ci];
  x1out[((size_t)b * NN + n) * CC + co] = acc;
}

// ============ Wasserstein: bitonic sort 1024 per (b,c), sum |s1-s2| ============
__global__ __launch_bounds__(256) void wass_k(const float* __restrict__ x1,
    const float* __restrict__ x2, float* __restrict__ part) {
  int bc = blockIdx.x;
  int b = bc >> 8, c = bc & 255;
  __shared__ float s1[1024];
  __shared__ float s2[1024];
  __shared__ float red[256];
  int t = threadIdx.x;
  for (int q = 0; q < 4; ++q) {
    int n = t + q * 256;
    s1[n] = x1[((size_t)b * NN + n) * CC + c];
    s2[n] = x2[((size_t)b * NN + n) * CC + c];
  }
  __syncthreads();
  for (int k = 2; k <= 1024; k <<= 1) {
    for (int j = k >> 1; j > 0; j >>= 1) {
      #pragma unroll
      for (int q = 0; q < 2; ++q) {
        int idx = t + q * 256;
        int i = ((idx & ~(j - 1)) << 1) | (idx & (j - 1));
        int l = i | j;
        bool up = ((i & k) == 0);
        float a = s1[i], bvv = s1[l];
        if ((a > bvv) == up) { s1[i] = bvv; s1[l] = a; }
        a = s2[i]; bvv = s2[l];
        if ((a > bvv) == up) { s2[i] = bvv; s2[l] = a; }
      }
      __syncthreads();
    }
  }
  float s = 0.f;
  for (int q = 0; q < 4; ++q) {
    int n = t + q * 256;
    s += fabsf(s1[n] - s2[n]);
  }
  red[t] = s;
  __syncthreads();
  for (int o = 128; o; o >>= 1) {
    if (t < o) red[t] += red[t + o];
    __syncthreads();
  }
  if (!t) part[bc] = red[0];
}

// ============ finalize losses ============
__global__ __launch_bounds__(256) void finalize_k(const float* __restrict__ logacc,
    const float* __restrict__ part, float* __restrict__ out) {
  int t = threadIdx.x;
  __shared__ double red[256];
  double s = 0.0;
  for (int i = t; i < 2048; i += 256) s += (double)part[i];
  red[t] = s;
  __syncthreads();
  for (int o = 128; o; o >>= 1) {
    if (t < o) red[t] += red[t + o];
    __syncthreads();
  }
  if (!t) {
    double l1 = 0.0, l2 = 0.0;
    for (int i = 0; i < 8; ++i) { l1 += (double)logacc[i]; l2 += (double)logacc[8 + i]; }
    out[OUT_L + 0] = (float)(-l1 / 8.0);
    out[OUT_L + 1] = (float)(-l2 / 8.0);
    out[OUT_L + 2] = (float)(red[0] / 2097152.0);
  }
}

extern "C" void kernel_launch(void* const* d_in, const int* in_sizes, int n_in,
                              void* d_out, int out_size, void* d_ws, size_t ws_size,
                              hipStream_t stream) {
  (void)in_sizes; (void)n_in; (void)out_size; (void)ws_size;
  const float* G1 = (const float*)d_in[0];
  const float* G2 = (const float*)d_in[1];
  const float* R1 = (const float*)d_in[2];
  const float* R2 = (const float*)d_in[3];
  const float* U1 = (const float*)d_in[7];
  const float* U2 = (const float*)d_in[8];
  const float* CW = (const float*)d_in[9];
  const float* CB = (const float*)d_in[10];
  const float* BG = (const float*)d_in[11];
  const float* BBt = (const float*)d_in[12];
  float* out = (float*)d_out;
  float* ws = (float*)d_ws;

  float* Alu    = ws + OFF_ALU;
  float* logacc = ws + OFF_LOGACC;
  int*   prm    = (int*)(ws + OFF_PIV);
  float* deg    = ws + OFF_DEG;
  float* R2n    = ws + OFF_R2N;
  float* LR2    = ws + OFF_LR2;
  float* LR1    = ws + OFF_LR1;
  float* X1P    = ws + OFF_X1P;
  float* CS1    = ws + OFF_CS1;
  float* CS2    = ws + OFF_CS2;
  float* BNP    = ws + OFF_BNP;
  float* BNS    = ws + OFF_BNS;
  float* WSP    = ws + OFF_WSP;

  pool_pair_k<<<dim3(136, 1, 16), 256, 0, stream>>>(G1, G2, U1, U2, out, Alu);
  deg_k<<<4096, 256, 0, stream>>>(out, deg);

  bn_partial_k<<<64, 256, 0, stream>>>(R2, BNP);
  bn_final_k<<<1, 256, 0, stream>>>(BNP, BG, BBt, BNS);
  bn_apply_k<<<8192, 256, 0, stream>>>(R2, BNS, R2n);
  colsum2_k<<<8, 256, 0, stream>>>(R2n, CS2);
  colsum1_k<<<1, 64, 0, stream>>>(R1, CS1);

  // x1 path
  gemv4_k<<<2048, 256, 0, stream>>>(out, R1, deg, CS1, LR1, 0);
  gemv4_k<<<2048, 256, 0, stream>>>(out, LR1, deg, CS1, X1P, 1);
  conv_k<<<8192, 256, 0, stream>>>(X1P, CW, CB, out + OUT_X1);

  // x2 path
  lgemm2_k<<<dim3(64, 8), 256, 0, stream>>>(out + OUT_G2P, R2n, deg + 8192, CS2, LR2, 0);
  lgemm2_k<<<dim3(64, 8), 256, 0, stream>>>(out + OUT_G2P, LR2, deg + 8192, CS2, out + OUT_X2, 1);

  // blocked LU (NB=64, 1-row-per-thread panels) on A = Gp + 1e-3 I (16 matrices)
  for (int p = 0; p < NN / 64; ++p) {
    lu_panel64_k<<<16, 1024, 0, stream>>>(Alu, p, logacc, prm);
    int rem = NN - (p + 1) * 64;
    if (rem > 0) {
      lu_swaptrsm64_k<<<dim3((rem + 255) / 256, 16), 256, 0, stream>>>(Alu, p, prm);
      int mt = (rem + 127) / 128;
      lu_gemm64_k<<<dim3(mt, mt, 16), 256, 0, stream>>>(Alu, p);
    }
  }

  wass_k<<<2048, 256, 0, stream>>>(out + OUT_X1, out + OUT_X2, WSP);
  finalize_k<<<1, 256, 0, stream>>>(logacc, WSP, out);
}

// Round 5
// 1998.685 us; speedup vs baseline: 2.9507x; 1.8212x over previous
//
#include <hip/hip_runtime.h>

#define NN 1024
#define CC 256

// ---- output offsets (floats) ----
constexpr size_t OUT_G2P = 8ull * NN * NN;
constexpr size_t OUT_X1  = 16ull * NN * NN;
constexpr size_t OUT_X2  = OUT_X1 + 8ull * NN * CC;
constexpr size_t OUT_L   = OUT_X2 + 8ull * NN * CC;

// ---- workspace offsets (floats) ----
constexpr size_t OFF_ALU    = 0;                        // 16M floats
constexpr size_t OFF_LOGACC = 16ull * NN * NN;          // 256
constexpr size_t OFF_DEG    = OFF_LOGACC + 256;         // 16384
constexpr size_t OFF_R2N    = OFF_DEG + 16384;          // 2097152
constexpr size_t OFF_LR2    = OFF_R2N + 2097152;        // 2097152
constexpr size_t OFF_LR1    = OFF_LR2 + 2097152;        // 32768
constexpr size_t OFF_X1P    = OFF_LR1 + 32768;          // 32768
constexpr size_t OFF_CS1    = OFF_X1P + 32768;          // 256
constexpr size_t OFF_CS2    = OFF_CS1 + 256;            // 2048
constexpr size_t OFF_BNP    = OFF_CS2 + 2048;           // 32768
constexpr size_t OFF_BNS    = OFF_BNP + 32768;          // 1024
constexpr size_t OFF_WSP    = OFF_BNS + 1024;           // 2048

// ============ pooling (pair tiles): Gp = 0.5*(W + W^T), A = Gp + 1e-3 I ============
__global__ __launch_bounds__(256) void pool_pair_k(const float* __restrict__ G1,
    const float* __restrict__ G2, const float* __restrict__ U1,
    const float* __restrict__ U2, float* __restrict__ out, float* __restrict__ Alu) {
  int mat = blockIdx.z, g = mat >> 3, b = mat & 7;
  const float* G = (g ? G2 : G1) + (size_t)b * NN * NN;
  const float* U = g ? U2 : U1;
  float* Gp = out + (size_t)mat * NN * NN;
  float* A  = Alu + (size_t)mat * NN * NN;

  int pid = blockIdx.x;
  int ti = 0, rem = pid;
  while (rem >= 16 - ti) { rem -= 16 - ti; ++ti; }
  int tj = ti + rem;

  int tc = threadIdx.x & 63, tr = threadIdx.x >> 6;
  __shared__ float Wa[64][65];
  __shared__ float Wb[64][65];
  #pragma unroll
  for (int s = 0; s < 16; ++s) {
    int r = s * 4 + tr;
    size_t ia = (size_t)(ti * 64 + r) * NN + tj * 64 + tc;
    size_t ib = (size_t)(tj * 64 + r) * NN + ti * 64 + tc;
    Wa[r][tc] = U[ia] * G[ia];
    Wb[r][tc] = U[ib] * G[ib];
  }
  __syncthreads();
  #pragma unroll
  for (int s = 0; s < 16; ++s) {
    int r = s * 4 + tr;
    float o1 = 0.5f * (Wa[r][tc] + Wb[tc][r]);
    size_t idx1 = (size_t)(ti * 64 + r) * NN + tj * 64 + tc;
    Gp[idx1] = o1;
    A[idx1] = o1 + ((ti == tj && r == tc) ? 1e-3f : 0.0f);
    if (ti != tj) {
      float o2 = 0.5f * (Wb[r][tc] + Wa[tc][r]);
      size_t idx2 = (size_t)(tj * 64 + r) * NN + ti * 64 + tc;
      Gp[idx2] = o2;
      A[idx2] = o2;
    }
  }
}

// ============ deg[b,i] = sum_j Gp[b,i,j] ============
__global__ __launch_bounds__(256) void deg_k(const float* __restrict__ out,
                                             float* __restrict__ deg) {
  int wid = threadIdx.x >> 6, lane = threadIdx.x & 63;
  int row = blockIdx.x * 4 + wid;
  const float* Gp = out + (size_t)row * NN;
  float s = 0.f;
  for (int k = lane; k < NN; k += 64) s += Gp[k];
  #pragma unroll
  for (int o = 32; o; o >>= 1) s += __shfl_down(s, o, 64);
  if (!lane) deg[row] = s;
}

// ============ batchnorm ============
__global__ __launch_bounds__(256) void bn_partial_k(const float* __restrict__ R2,
                                                    float* __restrict__ part) {
  int w = blockIdx.x, c = threadIdx.x;
  float s = 0.f, s2 = 0.f;
  for (int r = w * 128; r < (w + 1) * 128; ++r) {
    float x = R2[(size_t)r * CC + c];
    s += x; s2 += x * x;
  }
  part[w * 512 + c] = s;
  part[w * 512 + 256 + c] = s2;
}

__global__ __launch_bounds__(256) void bn_final_k(const float* __restrict__ part,
    const float* __restrict__ g, const float* __restrict__ bt, float* __restrict__ stats) {
  int c = threadIdx.x;
  float s = 0.f, s2 = 0.f;
  for (int w = 0; w < 64; ++w) { s += part[w * 512 + c]; s2 += part[w * 512 + 256 + c]; }
  float mu = s / 8192.0f, var = s2 / 8192.0f - mu * mu;
  stats[c] = mu;
  stats[256 + c] = rsqrtf(var + 1e-5f) * g[c];
  stats[512 + c] = bt[c];
}

__global__ __launch_bounds__(256) void bn_apply_k(const float* __restrict__ R2,
    const float* __restrict__ stats, float* __restrict__ R2n) {
  int c = threadIdx.x;
  size_t i = (size_t)blockIdx.x * CC + c;
  R2n[i] = (R2[i] - stats[c]) * stats[256 + c] + stats[512 + c];
}

// ============ column sums ============
__global__ __launch_bounds__(256) void colsum2_k(const float* __restrict__ R2n,
                                                 float* __restrict__ cs2) {
  int b = blockIdx.x, c = threadIdx.x;
  float s = 0.f;
  for (int n = 0; n < NN; ++n) s += R2n[((size_t)b * NN + n) * CC + c];
  cs2[b * CC + c] = s;
}

__global__ __launch_bounds__(64) void colsum1_k(const float* __restrict__ R1,
                                                float* __restrict__ cs1) {
  int t = threadIdx.x;
  if (t >= 32) return;
  int b = t >> 2, c = t & 3;
  float s = 0.f;
  for (int n = 0; n < NN; ++n) s += R1[((size_t)b * NN + n) * 4 + c];
  cs1[b * 4 + c] = s;
}

// ============ unpivoted LU of 64x64 diagonal block, in LDS ============
__global__ __launch_bounds__(256, 1) void lu_tiny_k(float* __restrict__ Alu, int p,
                                                    float* __restrict__ logacc) {
  const int mat = blockIdx.x;
  float* A = Alu + (size_t)mat * NN * NN;
  const int k0 = p * 64;
  const int tid = threadIdx.x;
  __shared__ float T[64][65];

  for (int t = tid; t < 64 * 64; t += 256) {
    int r = t >> 6, c = t & 63;
    T[r][c] = A[(size_t)(k0 + r) * NN + k0 + c];
  }
  __syncthreads();

  const int ro = tid & 63;   // row offset within trailing block
  const int cq = tid >> 6;   // column quarter 0..3

  #pragma unroll 1
  for (int j = 0; j < 64; ++j) {
    const int rr = j + 1 + ro;
    float lm = 0.0f;
    if (rr < 64) {
      const float pv = T[j][j];
      const float pvs = (fabsf(pv) < 1e-30f) ? copysignf(1e-30f, pv) : pv;
      lm = T[rr][j] / pvs;                      // all 4 quarters compute same lm
      for (int c = j + 1 + cq; c < 64; c += 4)  // strided col partition
        T[rr][c] -= lm * T[j][c];
    }
    __syncthreads();
    // deferred L-write (col j never touched again before final barrier)
    if (rr < 64 && cq == 0) T[rr][j] = lm;
  }
  __syncthreads();

  // log-sum of |diag|
  if (tid < 64) {
    float lg = logf(fmaxf(fabsf(T[tid][tid]), 1e-37f));
    #pragma unroll
    for (int o = 32; o; o >>= 1) lg += __shfl_down(lg, o, 64);
    if (tid == 0) {
      if (p == 0) logacc[mat] = lg;
      else        logacc[mat] += lg;
    }
  }
  __syncthreads();
  for (int t = tid; t < 64 * 64; t += 256) {
    int r = t >> 6, c = t & 63;
    A[(size_t)(k0 + r) * NN + k0 + c] = T[r][c];
  }
}

// ============ TRSM both sides: U12 = L11^-1 A12 (cols), L21 = A21 U11^-1 (rows) ============
__global__ __launch_bounds__(256, 1) void lu_trsm_k(float* __restrict__ Alu, int p) {
  const int mat = blockIdx.y;
  float* A = Alu + (size_t)mat * NN * NN;
  const int k0 = p * 64, base = k0 + 64;
  const int rem = NN - base;
  const int nb = (rem + 255) >> 8;

  __shared__ float B[64][65];   // combined L11\U11 factored block
  __shared__ float invd[64];
  for (int t = threadIdx.x; t < 64 * 64; t += 256) {
    int r = t >> 6, c = t & 63;
    B[r][c] = A[(size_t)(k0 + r) * NN + k0 + c];
  }
  __syncthreads();
  if (threadIdx.x < 64) {
    float d = B[threadIdx.x][threadIdx.x];
    invd[threadIdx.x] = 1.0f / ((fabsf(d) < 1e-30f) ? copysignf(1e-30f, d) : d);
  }
  __syncthreads();

  if ((int)blockIdx.x < nb) {
    // column solve: U12 col = L11^{-1} a  (unit lower)
    int col = base + blockIdx.x * 256 + threadIdx.x;
    if (col >= NN) return;
    float u[64];
    #pragma unroll
    for (int r = 0; r < 64; ++r) u[r] = A[(size_t)(k0 + r) * NN + col];
    #pragma unroll
    for (int l = 0; l < 64; ++l) {
      const float ul = u[l];
      #pragma unroll
      for (int r = l + 1; r < 64; ++r) u[r] -= B[r][l] * ul;
    }
    #pragma unroll
    for (int r = 0; r < 64; ++r) A[(size_t)(k0 + r) * NN + col] = u[r];
  } else {
    // row solve: L21 row = a U11^{-1}
    int row = base + (blockIdx.x - nb) * 256 + threadIdx.x;
    if (row >= NN) return;
    float x[64];
    const float4* Ar = reinterpret_cast<const float4*>(A + (size_t)row * NN + k0);
    #pragma unroll
    for (int c4 = 0; c4 < 16; ++c4) {
      float4 v = Ar[c4];
      x[c4 * 4 + 0] = v.x; x[c4 * 4 + 1] = v.y;
      x[c4 * 4 + 2] = v.z; x[c4 * 4 + 3] = v.w;
    }
    #pragma unroll
    for (int l = 0; l < 64; ++l) {
      x[l] *= invd[l];
      const float xl = x[l];
      #pragma unroll
      for (int j2 = l + 1; j2 < 64; ++j2) x[j2] -= xl * B[l][j2];
    }
    float4* Aw = reinterpret_cast<float4*>(A + (size_t)row * NN + k0);
    #pragma unroll
    for (int c4 = 0; c4 < 16; ++c4) {
      float4 v = {x[c4 * 4 + 0], x[c4 * 4 + 1], x[c4 * 4 + 2], x[c4 * 4 + 3]};
      Aw[c4] = v;
    }
  }
}

// ============ Schur update: A22 -= L21 @ U12 (128x128 tile, K=64) ============
__global__ __launch_bounds__(256) void lu_gemm64_k(float* __restrict__ Alu, int p) {
  int mat = blockIdx.z;
  float* A = Alu + (size_t)mat * NN * NN;
  int k0 = p * 64;
  int base = k0 + 64;
  int r0 = base + blockIdx.y * 128, c0 = base + blockIdx.x * 128;
  __shared__ float Ls[128][36];
  __shared__ float Us[32][132];
  int tid = threadIdx.x, tx = tid & 15, ty = tid >> 4;
  float acc[8][8] = {};
  for (int kk = 0; kk < 64; kk += 32) {
    for (int t = tid; t < 1024; t += 256) {
      int r = t >> 3, cc4 = (t & 7) * 4;
      float4 v = {0.f, 0.f, 0.f, 0.f};
      if (r0 + r < NN)
        v = *reinterpret_cast<const float4*>(A + (size_t)(r0 + r) * NN + k0 + kk + cc4);
      *reinterpret_cast<float4*>(&Ls[r][cc4]) = v;
    }
    for (int t = tid; t < 1024; t += 256) {
      int r = t >> 5, cc4 = (t & 31) * 4;
      float4 v = {0.f, 0.f, 0.f, 0.f};
      if (c0 + cc4 < NN)
        v = *reinterpret_cast<const float4*>(A + (size_t)(k0 + kk + r) * NN + c0 + cc4);
      *reinterpret_cast<float4*>(&Us[r][cc4]) = v;
    }
    __syncthreads();
    #pragma unroll 8
    for (int l = 0; l < 32; ++l) {
      float a[8], bv[8];
      #pragma unroll
      for (int q = 0; q < 4; ++q) {
        a[q]     = Ls[ty * 4 + q][l];
        a[q + 4] = Ls[64 + ty * 4 + q][l];
      }
      #pragma unroll
      for (int r = 0; r < 4; ++r) {
        bv[r]     = Us[l][tx * 4 + r];
        bv[r + 4] = Us[l][64 + tx * 4 + r];
      }
      #pragma unroll
      for (int q = 0; q < 8; ++q)
        #pragma unroll
        for (int r = 0; r < 8; ++r) acc[q][r] += a[q] * bv[r];
    }
    __syncthreads();
  }
  #pragma unroll
  for (int q = 0; q < 8; ++q) {
    int rr = r0 + ((q < 4) ? ty * 4 + q : 64 + ty * 4 + q - 4);
    if (rr < NN) {
      #pragma unroll
      for (int r = 0; r < 8; ++r) {
        int cc = c0 + ((r < 4) ? tx * 4 + r : 64 + tx * 4 + r - 4);
        if (cc < NN) A[(size_t)rr * NN + cc] -= acc[q][r];
      }
    }
  }
}

// ============ thin GEMV: C=4 path ============
__global__ __launch_bounds__(256) void gemv4_k(const float* __restrict__ Gp,
    const float* __restrict__ V, const float* __restrict__ deg,
    const float* __restrict__ cs, float* __restrict__ O, int mode) {
  int wid = threadIdx.x >> 6, lane = threadIdx.x & 63;
  int row = blockIdx.x * 4 + wid;
  int b = row >> 10, i = row & 1023;
  const float* Gr = Gp + (size_t)b * NN * NN + (size_t)i * NN;
  const float* Vb = V + (size_t)b * NN * 4;
  float a0 = 0.f, a1 = 0.f, a2 = 0.f, a3 = 0.f;
  for (int k = lane; k < NN; k += 64) {
    float g = Gr[k];
    float4 v = *reinterpret_cast<const float4*>(Vb + (size_t)k * 4);
    a0 += g * v.x; a1 += g * v.y; a2 += g * v.z; a3 += g * v.w;
  }
  #pragma unroll
  for (int o = 32; o; o >>= 1) {
    a0 += __shfl_down(a0, o, 64); a1 += __shfl_down(a1, o, 64);
    a2 += __shfl_down(a2, o, 64); a3 += __shfl_down(a3, o, 64);
  }
  if (lane == 0) {
    float4 v = *reinterpret_cast<const float4*>(Vb + (size_t)i * 4);
    float dg = deg[row];
    float r0 = dg * v.x - a0, r1 = dg * v.y - a1;
    float r2 = dg * v.z - a2, r3 = dg * v.w - a3;
    if (mode) {
      r0 = 2.f * r0 + v.x + cs[b * 4 + 0];
      r1 = 2.f * r1 + v.y + cs[b * 4 + 1];
      r2 = 2.f * r2 + v.z + cs[b * 4 + 2];
      r3 = 2.f * r3 + v.w + cs[b * 4 + 3];
    }
    float4 o4 = {r0, r1, r2, r3};
    *reinterpret_cast<float4*>(O + (size_t)row * 4) = o4;
  }
}

// ============ L-apply GEMM (C=256): O = deg*V - Gp@V [m0]; 2*that + V + cs [m1] ============
__global__ __launch_bounds__(256) void lgemm2_k(const float* __restrict__ Gp,
    const float* __restrict__ V, const float* __restrict__ deg,
    const float* __restrict__ cs, float* __restrict__ O, int mode) {
  int b = blockIdx.y;
  int i0 = blockIdx.x * 16;
  const float* G = Gp + (size_t)b * NN * NN;
  const float* Vb = V + (size_t)b * NN * CC;
  __shared__ float Gs[16][36];
  __shared__ float Vs[32][256];
  int tid = threadIdx.x;
  int c4 = (tid & 63) * 4, rg = tid >> 6;
  float acc[4][4] = {};
  for (int kk = 0; kk < NN; kk += 32) {
    if (tid < 128) {
      int r = tid >> 3, cc4 = (tid & 7) * 4;
      float4 g = *reinterpret_cast<const float4*>(G + (size_t)(i0 + r) * NN + kk + cc4);
      *reinterpret_cast<float4*>(&Gs[r][cc4]) = g;
    }
    #pragma unroll
    for (int it = 0; it < 8; ++it) {
      int idx = tid + it * 256;
      int r = idx >> 6, vc4 = (idx & 63) * 4;
      float4 v = *reinterpret_cast<const float4*>(Vb + (size_t)(kk + r) * CC + vc4);
      *reinterpret_cast<float4*>(&Vs[r][vc4]) = v;
    }
    __syncthreads();
    #pragma unroll
    for (int k4 = 0; k4 < 8; ++k4) {
      float4 g0 = *reinterpret_cast<const float4*>(&Gs[rg * 4 + 0][k4 * 4]);
      float4 g1 = *reinterpret_cast<const float4*>(&Gs[rg * 4 + 1][k4 * 4]);
      float4 g2 = *reinterpret_cast<const float4*>(&Gs[rg * 4 + 2][k4 * 4]);
      float4 g3 = *reinterpret_cast<const float4*>(&Gs[rg * 4 + 3][k4 * 4]);
      float4 v0 = *reinterpret_cast<const float4*>(&Vs[k4 * 4 + 0][c4]);
      float4 v1 = *reinterpret_cast<const float4*>(&Vs[k4 * 4 + 1][c4]);
      float4 v2 = *reinterpret_cast<const float4*>(&Vs[k4 * 4 + 2][c4]);
      float4 v3 = *reinterpret_cast<const float4*>(&Vs[k4 * 4 + 3][c4]);
      float ga[4][4] = {{g0.x, g0.y, g0.z, g0.w}, {g1.x, g1.y, g1.z, g1.w},
                        {g2.x, g2.y, g2.z, g2.w}, {g3.x, g3.y, g3.z, g3.w}};
      float va[4][4] = {{v0.x, v0.y, v0.z, v0.w}, {v1.x, v1.y, v1.z, v1.w},
                        {v2.x, v2.y, v2.z, v2.w}, {v3.x, v3.y, v3.z, v3.w}};
      #pragma unroll
      for (int kq = 0; kq < 4; ++kq)
        #pragma unroll
        for (int q = 0; q < 4; ++q)
          #pragma unroll
          for (int r = 0; r < 4; ++r) acc[q][r] += ga[q][kq] * va[kq][r];
    }
    __syncthreads();
  }
  #pragma unroll
  for (int q = 0; q < 4; ++q) {
    int i = i0 + rg * 4 + q;
    float dg = deg[b * NN + i];
    float4 vv = *reinterpret_cast<const float4*>(Vb + (size_t)i * CC + c4);
    float vo[4] = {vv.x, vv.y, vv.z, vv.w};
    float res[4];
    #pragma unroll
    for (int r = 0; r < 4; ++r) res[r] = dg * vo[r] - acc[q][r];
    if (mode) {
      float4 cv = *reinterpret_cast<const float4*>(cs + b * CC + c4);
      float co[4] = {cv.x, cv.y, cv.z, cv.w};
      #pragma unroll
      for (int r = 0; r < 4; ++r) res[r] = 2.f * res[r] + vo[r] + co[r];
    }
    float4 o4 = {res[0], res[1], res[2], res[3]};
    *reinterpret_cast<float4*>(O + ((size_t)b * NN + i) * CC + c4) = o4;
  }
}

// ============ conv1d: [B,N,4] -> [B,N,256], K=5, pad 2 ============
__global__ __launch_bounds__(256) void conv_k(const float* __restrict__ xp,
    const float* __restrict__ w, const float* __restrict__ bias,
    float* __restrict__ x1out) {
  int bn = blockIdx.x;
  int b = bn >> 10, n = bn & 1023;
  int co = threadIdx.x;
  __shared__ float xs[5][4];
  if (threadIdx.x < 20) {
    int k = threadIdx.x >> 2, ci = threadIdx.x & 3;
    int n2 = n + k - 2;
    xs[k][ci] = (n2 >= 0 && n2 < NN) ? xp[((size_t)b * NN + n2) * 4 + ci] : 0.0f;
  }
  __syncthreads();
  const float* wp = w + co * 20;
  float acc = bias[co];
  #pragma unroll
  for (int ci = 0; ci < 4; ++ci)
    #pragma unroll
    for (int k = 0; k < 5; ++k) acc += wp[ci * 5 + k] * xs[k][ci];
  x1out[((size_t)b * NN + n) * CC + co] = acc;
}

// ============ Wasserstein: bitonic sort 1024 per (b,c), sum |s1-s2| ============
__global__ __launch_bounds__(256) void wass_k(const float* __restrict__ x1,
    const float* __restrict__ x2, float* __restrict__ part) {
  int bc = blockIdx.x;
  int b = bc >> 8, c = bc & 255;
  __shared__ float s1[1024];
  __shared__ float s2[1024];
  __shared__ float red[256];
  int t = threadIdx.x;
  for (int q = 0; q < 4; ++q) {
    int n = t + q * 256;
    s1[n] = x1[((size_t)b * NN + n) * CC + c];
    s2[n] = x2[((size_t)b * NN + n) * CC + c];
  }
  __syncthreads();
  for (int k = 2; k <= 1024; k <<= 1) {
    for (int j = k >> 1; j > 0; j >>= 1) {
      #pragma unroll
      for (int q = 0; q < 2; ++q) {
        int idx = t + q * 256;
        int i = ((idx & ~(j - 1)) << 1) | (idx & (j - 1));
        int l = i | j;
        bool up = ((i & k) == 0);
        float a = s1[i], bvv = s1[l];
        if ((a > bvv) == up) { s1[i] = bvv; s1[l] = a; }
        a = s2[i]; bvv = s2[l];
        if ((a > bvv) == up) { s2[i] = bvv; s2[l] = a; }
      }
      __syncthreads();
    }
  }
  float s = 0.f;
  for (int q = 0; q < 4; ++q) {
    int n = t + q * 256;
    s += fabsf(s1[n] - s2[n]);
  }
  red[t] = s;
  __syncthreads();
  for (int o = 128; o; o >>= 1) {
    if (t < o) red[t] += red[t + o];
    __syncthreads();
  }
  if (!t) part[bc] = red[0];
}

// ============ finalize losses ============
__global__ __launch_bounds__(256) void finalize_k(const float* __restrict__ logacc,
    const float* __restrict__ part, float* __restrict__ out) {
  int t = threadIdx.x;
  __shared__ double red[256];
  double s = 0.0;
  for (int i = t; i < 2048; i += 256) s += (double)part[i];
  red[t] = s;
  __syncthreads();
  for (int o = 128; o; o >>= 1) {
    if (t < o) red[t] += red[t + o];
    __syncthreads();
  }
  if (!t) {
    double l1 = 0.0, l2 = 0.0;
    for (int i = 0; i < 8; ++i) { l1 += (double)logacc[i]; l2 += (double)logacc[8 + i]; }
    out[OUT_L + 0] = (float)(-l1 / 8.0);
    out[OUT_L + 1] = (float)(-l2 / 8.0);
    out[OUT_L + 2] = (float)(red[0] / 2097152.0);
  }
}

extern "C" void kernel_launch(void* const* d_in, const int* in_sizes, int n_in,
                              void* d_out, int out_size, void* d_ws, size_t ws_size,
                              hipStream_t stream) {
  (void)in_sizes; (void)n_in; (void)out_size; (void)ws_size;
  const float* G1 = (const float*)d_in[0];
  const float* G2 = (const float*)d_in[1];
  const float* R1 = (const float*)d_in[2];
  const float* R2 = (const float*)d_in[3];
  const float* U1 = (const float*)d_in[7];
  const float* U2 = (const float*)d_in[8];
  const float* CW = (const float*)d_in[9];
  const float* CB = (const float*)d_in[10];
  const float* BG = (const float*)d_in[11];
  const float* BBt = (const float*)d_in[12];
  float* out = (float*)d_out;
  float* ws = (float*)d_ws;

  float* Alu    = ws + OFF_ALU;
  float* logacc = ws + OFF_LOGACC;
  float* deg    = ws + OFF_DEG;
  float* R2n    = ws + OFF_R2N;
  float* LR2    = ws + OFF_LR2;
  float* LR1    = ws + OFF_LR1;
  float* X1P    = ws + OFF_X1P;
  float* CS1    = ws + OFF_CS1;
  float* CS2    = ws + OFF_CS2;
  float* BNP    = ws + OFF_BNP;
  float* BNS    = ws + OFF_BNS;
  float* WSP    = ws + OFF_WSP;

  pool_pair_k<<<dim3(136, 1, 16), 256, 0, stream>>>(G1, G2, U1, U2, out, Alu);
  deg_k<<<4096, 256, 0, stream>>>(out, deg);

  bn_partial_k<<<64, 256, 0, stream>>>(R2, BNP);
  bn_final_k<<<1, 256, 0, stream>>>(BNP, BG, BBt, BNS);
  bn_apply_k<<<8192, 256, 0, stream>>>(R2, BNS, R2n);
  colsum2_k<<<8, 256, 0, stream>>>(R2n, CS2);
  colsum1_k<<<1, 64, 0, stream>>>(R1, CS1);

  // x1 path
  gemv4_k<<<2048, 256, 0, stream>>>(out, R1, deg, CS1, LR1, 0);
  gemv4_k<<<2048, 256, 0, stream>>>(out, LR1, deg, CS1, X1P, 1);
  conv_k<<<8192, 256, 0, stream>>>(X1P, CW, CB, out + OUT_X1);

  // x2 path
  lgemm2_k<<<dim3(64, 8), 256, 0, stream>>>(out + OUT_G2P, R2n, deg + 8192, CS2, LR2, 0);
  lgemm2_k<<<dim3(64, 8), 256, 0, stream>>>(out + OUT_G2P, LR2, deg + 8192, CS2, out + OUT_X2, 1);

  // blocked UNPIVOTED LU (NB=64): tiny diag LU + parallel 2-sided TRSM + Schur
  for (int p = 0; p < NN / 64; ++p) {
    lu_tiny_k<<<16, 256, 0, stream>>>(Alu, p, logacc);
    int rem = NN - (p + 1) * 64;
    if (rem > 0) {
      int nb = (rem + 255) / 256;
      lu_trsm_k<<<dim3(2 * nb, 16), 256, 0, stream>>>(Alu, p);
      int mt = (rem + 127) / 128;
      lu_gemm64_k<<<dim3(mt, mt, 16), 256, 0, stream>>>(Alu, p);
    }
  }

  wass_k<<<2048, 256, 0, stream>>>(out + OUT_X1, out + OUT_X2, WSP);
  finalize_k<<<1, 256, 0, stream>>>(logacc, WSP, out);
}

// Round 6
// 1846.159 us; speedup vs baseline: 3.1945x; 1.0826x over previous
//
#include <hip/hip_runtime.h>

#define NN 1024
#define CC 256

typedef short short8 __attribute__((ext_vector_type(8)));
typedef short short4v __attribute__((ext_vector_type(4)));
typedef float f32x4 __attribute__((ext_vector_type(4)));

// ---- output offsets (floats) ----
constexpr size_t OUT_G2P = 8ull * NN * NN;
constexpr size_t OUT_X1  = 16ull * NN * NN;
constexpr size_t OUT_X2  = OUT_X1 + 8ull * NN * CC;
constexpr size_t OUT_L   = OUT_X2 + 8ull * NN * CC;

// ---- workspace offsets (floats) ----
constexpr size_t OFF_ALU    = 0;                        // 16M floats
constexpr size_t OFF_LOGACC = 16ull * NN * NN;          // 256
constexpr size_t OFF_DEG    = OFF_LOGACC + 256;         // 16384
constexpr size_t OFF_R2N    = OFF_DEG + 16384;          // 2097152
constexpr size_t OFF_LR2    = OFF_R2N + 2097152;        // 2097152
constexpr size_t OFF_LR1    = OFF_LR2 + 2097152;        // 32768
constexpr size_t OFF_X1P    = OFF_LR1 + 32768;          // 32768
constexpr size_t OFF_CS1    = OFF_X1P + 32768;          // 256
constexpr size_t OFF_CS2    = OFF_CS1 + 256;            // 2048
constexpr size_t OFF_BNP    = OFF_CS2 + 2048;           // 32768
constexpr size_t OFF_BNS    = OFF_BNP + 32768;          // 1024
constexpr size_t OFF_WSP    = OFF_BNS + 1024;           // 2048
constexpr size_t OFF_CSP    = OFF_WSP + 2048;           // 32768 (colsum partials)

__device__ __forceinline__ unsigned short f2bf(float f) {
  unsigned u = __float_as_uint(f);
  unsigned r = (u + 0x7FFFu + ((u >> 16) & 1u)) >> 16;
  return (unsigned short)r;
}

// ============ pooling (pair tiles): Gp = 0.5*(W + W^T), A = Gp + 1e-3 I ============
__global__ __launch_bounds__(256) void pool_pair_k(const float* __restrict__ G1,
    const float* __restrict__ G2, const float* __restrict__ U1,
    const float* __restrict__ U2, float* __restrict__ out, float* __restrict__ Alu) {
  int mat = blockIdx.z, g = mat >> 3, b = mat & 7;
  const float* G = (g ? G2 : G1) + (size_t)b * NN * NN;
  const float* U = g ? U2 : U1;
  float* Gp = out + (size_t)mat * NN * NN;
  float* A  = Alu + (size_t)mat * NN * NN;

  int pid = blockIdx.x;
  int ti = 0, rem = pid;
  while (rem >= 16 - ti) { rem -= 16 - ti; ++ti; }
  int tj = ti + rem;

  int tc = threadIdx.x & 63, tr = threadIdx.x >> 6;
  __shared__ float Wa[64][65];
  __shared__ float Wb[64][65];
  #pragma unroll
  for (int s = 0; s < 16; ++s) {
    int r = s * 4 + tr;
    size_t ia = (size_t)(ti * 64 + r) * NN + tj * 64 + tc;
    size_t ib = (size_t)(tj * 64 + r) * NN + ti * 64 + tc;
    Wa[r][tc] = U[ia] * G[ia];
    Wb[r][tc] = U[ib] * G[ib];
  }
  __syncthreads();
  #pragma unroll
  for (int s = 0; s < 16; ++s) {
    int r = s * 4 + tr;
    float o1 = 0.5f * (Wa[r][tc] + Wb[tc][r]);
    size_t idx1 = (size_t)(ti * 64 + r) * NN + tj * 64 + tc;
    Gp[idx1] = o1;
    A[idx1] = o1 + ((ti == tj && r == tc) ? 1e-3f : 0.0f);
    if (ti != tj) {
      float o2 = 0.5f * (Wb[r][tc] + Wa[tc][r]);
      size_t idx2 = (size_t)(tj * 64 + r) * NN + ti * 64 + tc;
      Gp[idx2] = o2;
      A[idx2] = o2;
    }
  }
}

// ============ deg[b,i] = sum_j Gp[b,i,j] ============
__global__ __launch_bounds__(256) void deg_k(const float* __restrict__ out,
                                             float* __restrict__ deg) {
  int wid = threadIdx.x >> 6, lane = threadIdx.x & 63;
  int row = blockIdx.x * 4 + wid;
  const float* Gp = out + (size_t)row * NN;
  float s = 0.f;
  for (int k = lane; k < NN; k += 64) s += Gp[k];
  #pragma unroll
  for (int o = 32; o; o >>= 1) s += __shfl_down(s, o, 64);
  if (!lane) deg[row] = s;
}

// ============ batchnorm ============
__global__ __launch_bounds__(256) void bn_partial_k(const float* __restrict__ R2,
                                                    float* __restrict__ part) {
  int w = blockIdx.x, c = threadIdx.x;
  float s = 0.f, s2 = 0.f;
  for (int r = w * 128; r < (w + 1) * 128; ++r) {
    float x = R2[(size_t)r * CC + c];
    s += x; s2 += x * x;
  }
  part[w * 512 + c] = s;
  part[w * 512 + 256 + c] = s2;
}

__global__ __launch_bounds__(256) void bn_final_k(const float* __restrict__ part,
    const float* __restrict__ g, const float* __restrict__ bt, float* __restrict__ stats) {
  int c = threadIdx.x;
  float s = 0.f, s2 = 0.f;
  for (int w = 0; w < 64; ++w) { s += part[w * 512 + c]; s2 += part[w * 512 + 256 + c]; }
  float mu = s / 8192.0f, var = s2 / 8192.0f - mu * mu;
  stats[c] = mu;
  stats[256 + c] = rsqrtf(var + 1e-5f) * g[c];
  stats[512 + c] = bt[c];
}

__global__ __launch_bounds__(256) void bn_apply_k(const float* __restrict__ R2,
    const float* __restrict__ stats, float* __restrict__ R2n) {
  int c = threadIdx.x;
  size_t i = (size_t)blockIdx.x * CC + c;
  R2n[i] = (R2[i] - stats[c]) * stats[256 + c] + stats[512 + c];
}

// ============ column sums (two-stage) ============
__global__ __launch_bounds__(256) void colsum2a_k(const float* __restrict__ R2n,
                                                  float* __restrict__ part) {
  int ch = blockIdx.x, b = blockIdx.y, c = threadIdx.x;
  float s = 0.f;
  for (int n = ch * 64; n < ch * 64 + 64; ++n)
    s += R2n[((size_t)b * NN + n) * CC + c];
  part[(ch * 8 + b) * 256 + c] = s;
}

__global__ __launch_bounds__(256) void colsum2b_k(const float* __restrict__ part,
                                                  float* __restrict__ cs2) {
  int b = blockIdx.x, c = threadIdx.x;
  float s = 0.f;
  #pragma unroll
  for (int ch = 0; ch < 16; ++ch) s += part[(ch * 8 + b) * 256 + c];
  cs2[b * 256 + c] = s;
}

__global__ __launch_bounds__(64) void colsum1_k(const float* __restrict__ R1,
                                                float* __restrict__ cs1) {
  int t = threadIdx.x;
  if (t >= 32) return;
  int b = t >> 2, c = t & 3;
  float s = 0.f;
  for (int n = 0; n < NN; ++n) s += R1[((size_t)b * NN + n) * 4 + c];
  cs1[b * 4 + c] = s;
}

// ============ transpose fp32 [b][1024][256] -> bf16 [b][256][1024] ============
__global__ __launch_bounds__(256) void transp_k(const float* __restrict__ src,
                                                unsigned short* __restrict__ dst) {
  int b = blockIdx.z;
  int n0 = blockIdx.x * 64, c0 = blockIdx.y * 64;
  __shared__ float Ts[64][68];
  int tid = threadIdx.x;
  #pragma unroll
  for (int s = 0; s < 4; ++s) {
    int idx = tid + s * 256;
    int r = idx >> 4, q = idx & 15;
    float4 v = *reinterpret_cast<const float4*>(&src[((size_t)b * NN + n0 + r) * CC + c0 + q * 4]);
    *reinterpret_cast<float4*>(&Ts[r][q * 4]) = v;
  }
  __syncthreads();
  #pragma unroll
  for (int s = 0; s < 2; ++s) {
    int idx = tid + s * 256;
    int cc = idx >> 3, g = idx & 7;
    short8 o;
    #pragma unroll
    for (int e = 0; e < 8; ++e) o[e] = (short)f2bf(Ts[g * 8 + e][cc]);
    *reinterpret_cast<short8*>(&dst[((size_t)b * CC + c0 + cc) * NN + n0 + g * 8]) = o;
  }
}

// ============ MFMA L-apply GEMM: O = deg*V - G@V [m0]; 2*that + V + cs [m1] ============
__global__ __launch_bounds__(256) void lgemm_mfma_k(const float* __restrict__ Gp,
    const unsigned short* __restrict__ Vt, const float* __restrict__ Vf,
    const float* __restrict__ deg, const float* __restrict__ cs,
    float* __restrict__ O, unsigned short* __restrict__ Ot, int mode) {
  const int b = blockIdx.z;
  const float* G = Gp + (size_t)b * NN * NN;
  const unsigned short* VT = Vt + (size_t)b * CC * NN;
  const int tid = threadIdx.x, l = tid & 63, w = tid >> 6;
  const int wm = w >> 1, wn = w & 1;
  const int m0 = blockIdx.x * 64, n0 = blockIdx.y * 64;
  const int lr = l & 15, lk = l >> 4;

  __shared__ unsigned short As[64][40];
  __shared__ unsigned short Bs[64][40];

  f32x4 acc00 = {0.f, 0.f, 0.f, 0.f}, acc01 = acc00, acc10 = acc00, acc11 = acc00;

  const int sr = tid >> 2, sk = (tid & 3) * 8;

  for (int kk = 0; kk < NN; kk += 32) {
    // stage A (fp32 -> bf16)
    {
      const float* gp = &G[(size_t)(m0 + sr) * NN + kk + sk];
      float4 g0 = *reinterpret_cast<const float4*>(gp);
      float4 g1 = *reinterpret_cast<const float4*>(gp + 4);
      short8 av;
      av[0] = (short)f2bf(g0.x); av[1] = (short)f2bf(g0.y);
      av[2] = (short)f2bf(g0.z); av[3] = (short)f2bf(g0.w);
      av[4] = (short)f2bf(g1.x); av[5] = (short)f2bf(g1.y);
      av[6] = (short)f2bf(g1.z); av[7] = (short)f2bf(g1.w);
      *reinterpret_cast<short8*>(&As[sr][sk]) = av;
      // stage B (already bf16, transposed)
      short8 bv = *reinterpret_cast<const short8*>(&VT[(size_t)(n0 + sr) * NN + kk + sk]);
      *reinterpret_cast<short8*>(&Bs[sr][sk]) = bv;
    }
    __syncthreads();
    short8 a0 = *reinterpret_cast<const short8*>(&As[wm * 32 + lr][lk * 8]);
    short8 a1 = *reinterpret_cast<const short8*>(&As[wm * 32 + 16 + lr][lk * 8]);
    short8 b0 = *reinterpret_cast<const short8*>(&Bs[wn * 32 + lr][lk * 8]);
    short8 b1 = *reinterpret_cast<const short8*>(&Bs[wn * 32 + 16 + lr][lk * 8]);
    acc00 = __builtin_amdgcn_mfma_f32_16x16x32_bf16(a0, b0, acc00, 0, 0, 0);
    acc01 = __builtin_amdgcn_mfma_f32_16x16x32_bf16(a0, b1, acc01, 0, 0, 0);
    acc10 = __builtin_amdgcn_mfma_f32_16x16x32_bf16(a1, b0, acc10, 0, 0, 0);
    acc11 = __builtin_amdgcn_mfma_f32_16x16x32_bf16(a1, b1, acc11, 0, 0, 0);
    __syncthreads();
  }

  // epilogue
  #pragma unroll
  for (int i = 0; i < 2; ++i) {
    #pragma unroll
    for (int j = 0; j < 2; ++j) {
      const f32x4 a = (i == 0) ? (j == 0 ? acc00 : acc01) : (j == 0 ? acc10 : acc11);
      const int row0 = m0 + wm * 32 + i * 16 + lk * 4;
      const int col  = n0 + wn * 32 + j * 16 + lr;
      float res[4];
      #pragma unroll
      for (int r = 0; r < 4; ++r) {
        const int row = row0 + r;
        const size_t off = ((size_t)b * NN + row) * CC + col;
        const float v = Vf[off];
        const float d = deg[(size_t)b * NN + row];
        float o = d * v - a[r];
        if (mode) o = 2.0f * o + v + cs[b * CC + col];
        O[off] = o;
        res[r] = o;
      }
      if (!mode) {
        short4v pk;
        #pragma unroll
        for (int r = 0; r < 4; ++r) pk[r] = (short)f2bf(res[r]);
        *reinterpret_cast<short4v*>(&Ot[((size_t)b * CC + col) * NN + row0]) = pk;
      }
    }
  }
}

// ============ unpivoted LU of 64x64 diagonal block, in LDS ============
__global__ __launch_bounds__(256, 1) void lu_tiny_k(float* __restrict__ Alu, int p,
                                                    float* __restrict__ logacc) {
  const int mat = blockIdx.x;
  float* A = Alu + (size_t)mat * NN * NN;
  const int k0 = p * 64;
  const int tid = threadIdx.x;
  __shared__ float T[64][65];

  for (int t = tid; t < 64 * 64; t += 256) {
    int r = t >> 6, c = t & 63;
    T[r][c] = A[(size_t)(k0 + r) * NN + k0 + c];
  }
  __syncthreads();

  const int ro = tid & 63;
  const int cq = tid >> 6;

  #pragma unroll 1
  for (int j = 0; j < 64; ++j) {
    const int rr = j + 1 + ro;
    float lm = 0.0f;
    if (rr < 64) {
      const float pv = T[j][j];
      const float pvs = (fabsf(pv) < 1e-30f) ? copysignf(1e-30f, pv) : pv;
      lm = T[rr][j] / pvs;
      for (int c = j + 1 + cq; c < 64; c += 4)
        T[rr][c] -= lm * T[j][c];
    }
    __syncthreads();
    if (rr < 64 && cq == 0) T[rr][j] = lm;
  }
  __syncthreads();

  if (tid < 64) {
    float lg = logf(fmaxf(fabsf(T[tid][tid]), 1e-37f));
    #pragma unroll
    for (int o = 32; o; o >>= 1) lg += __shfl_down(lg, o, 64);
    if (tid == 0) {
      if (p == 0) logacc[mat] = lg;
      else        logacc[mat] += lg;
    }
  }
  __syncthreads();
  for (int t = tid; t < 64 * 64; t += 256) {
    int r = t >> 6, c = t & 63;
    A[(size_t)(k0 + r) * NN + k0 + c] = T[r][c];
  }
}

// ============ TRSM both sides ============
__global__ __launch_bounds__(256, 1) void lu_trsm_k(float* __restrict__ Alu, int p) {
  const int mat = blockIdx.y;
  float* A = Alu + (size_t)mat * NN * NN;
  const int k0 = p * 64, base = k0 + 64;
  const int rem = NN - base;
  const int nb = (rem + 255) >> 8;

  __shared__ float B[64][65];
  __shared__ float invd[64];
  for (int t = threadIdx.x; t < 64 * 64; t += 256) {
    int r = t >> 6, c = t & 63;
    B[r][c] = A[(size_t)(k0 + r) * NN + k0 + c];
  }
  __syncthreads();
  if (threadIdx.x < 64) {
    float d = B[threadIdx.x][threadIdx.x];
    invd[threadIdx.x] = 1.0f / ((fabsf(d) < 1e-30f) ? copysignf(1e-30f, d) : d);
  }
  __syncthreads();

  if ((int)blockIdx.x < nb) {
    int col = base + blockIdx.x * 256 + threadIdx.x;
    if (col >= NN) return;
    float u[64];
    #pragma unroll
    for (int r = 0; r < 64; ++r) u[r] = A[(size_t)(k0 + r) * NN + col];
    #pragma unroll
    for (int l = 0; l < 64; ++l) {
      const float ul = u[l];
      #pragma unroll
      for (int r = l + 1; r < 64; ++r) u[r] -= B[r][l] * ul;
    }
    #pragma unroll
    for (int r = 0; r < 64; ++r) A[(size_t)(k0 + r) * NN + col] = u[r];
  } else {
    int row = base + (blockIdx.x - nb) * 256 + threadIdx.x;
    if (row >= NN) return;
    float x[64];
    const float4* Ar = reinterpret_cast<const float4*>(A + (size_t)row * NN + k0);
    #pragma unroll
    for (int c4 = 0; c4 < 16; ++c4) {
      float4 v = Ar[c4];
      x[c4 * 4 + 0] = v.x; x[c4 * 4 + 1] = v.y;
      x[c4 * 4 + 2] = v.z; x[c4 * 4 + 3] = v.w;
    }
    #pragma unroll
    for (int l = 0; l < 64; ++l) {
      x[l] *= invd[l];
      const float xl = x[l];
      #pragma unroll
      for (int j2 = l + 1; j2 < 64; ++j2) x[j2] -= xl * B[l][j2];
    }
    float4* Aw = reinterpret_cast<float4*>(A + (size_t)row * NN + k0);
    #pragma unroll
    for (int c4 = 0; c4 < 16; ++c4) {
      float4 v = {x[c4 * 4 + 0], x[c4 * 4 + 1], x[c4 * 4 + 2], x[c4 * 4 + 3]};
      Aw[c4] = v;
    }
  }
}

// ============ Schur update: A22 -= L21 @ U12 (128x128 tile, K=64, b128 LDS) ============
__global__ __launch_bounds__(256) void lu_gemm64_k(float* __restrict__ Alu, int p) {
  int mat = blockIdx.z;
  float* A = Alu + (size_t)mat * NN * NN;
  int k0 = p * 64;
  int base = k0 + 64;
  int r0 = base + blockIdx.y * 128, c0 = base + blockIdx.x * 128;
  __shared__ float LsT[32][132];
  __shared__ float Us[32][132];
  int tid = threadIdx.x, tx = tid & 15, ty = tid >> 4;
  float acc[8][8] = {};
  for (int kk = 0; kk < 64; kk += 32) {
    for (int t = tid; t < 1024; t += 256) {
      int r = t >> 3, cc4 = (t & 7) * 4;
      float4 v = {0.f, 0.f, 0.f, 0.f};
      if (r0 + r < NN)
        v = *reinterpret_cast<const float4*>(A + (size_t)(r0 + r) * NN + k0 + kk + cc4);
      LsT[cc4 + 0][r] = v.x; LsT[cc4 + 1][r] = v.y;
      LsT[cc4 + 2][r] = v.z; LsT[cc4 + 3][r] = v.w;
    }
    for (int t = tid; t < 1024; t += 256) {
      int r = t >> 5, cc4 = (t & 31) * 4;
      float4 v = {0.f, 0.f, 0.f, 0.f};
      if (c0 + cc4 < NN)
        v = *reinterpret_cast<const float4*>(A + (size_t)(k0 + kk + r) * NN + c0 + cc4);
      *reinterpret_cast<float4*>(&Us[r][cc4]) = v;
    }
    __syncthreads();
    #pragma unroll 8
    for (int l = 0; l < 32; ++l) {
      float4 fa0 = *reinterpret_cast<const float4*>(&LsT[l][ty * 4]);
      float4 fa1 = *reinterpret_cast<const float4*>(&LsT[l][64 + ty * 4]);
      float4 fb0 = *reinterpret_cast<const float4*>(&Us[l][tx * 4]);
      float4 fb1 = *reinterpret_cast<const float4*>(&Us[l][64 + tx * 4]);
      float a[8] = {fa0.x, fa0.y, fa0.z, fa0.w, fa1.x, fa1.y, fa1.z, fa1.w};
      float bv[8] = {fb0.x, fb0.y, fb0.z, fb0.w, fb1.x, fb1.y, fb1.z, fb1.w};
      #pragma unroll
      for (int q = 0; q < 8; ++q)
        #pragma unroll
        for (int r = 0; r < 8; ++r) acc[q][r] += a[q] * bv[r];
    }
    __syncthreads();
  }
  #pragma unroll
  for (int q = 0; q < 8; ++q) {
    int rr = r0 + ((q < 4) ? ty * 4 + q : 64 + ty * 4 + q - 4);
    if (rr < NN) {
      #pragma unroll
      for (int r = 0; r < 8; ++r) {
        int cc = c0 + ((r < 4) ? tx * 4 + r : 64 + tx * 4 + r - 4);
        if (cc < NN) A[(size_t)rr * NN + cc] -= acc[q][r];
      }
    }
  }
}

// ============ thin GEMV: C=4 path ============
__global__ __launch_bounds__(256) void gemv4_k(const float* __restrict__ Gp,
    const float* __restrict__ V, const float* __restrict__ deg,
    const float* __restrict__ cs, float* __restrict__ O, int mode) {
  int wid = threadIdx.x >> 6, lane = threadIdx.x & 63;
  int row = blockIdx.x * 4 + wid;
  int b = row >> 10, i = row & 1023;
  const float* Gr = Gp + (size_t)b * NN * NN + (size_t)i * NN;
  const float* Vb = V + (size_t)b * NN * 4;
  float a0 = 0.f, a1 = 0.f, a2 = 0.f, a3 = 0.f;
  for (int k = lane; k < NN; k += 64) {
    float g = Gr[k];
    float4 v = *reinterpret_cast<const float4*>(Vb + (size_t)k * 4);
    a0 += g * v.x; a1 += g * v.y; a2 += g * v.z; a3 += g * v.w;
  }
  #pragma unroll
  for (int o = 32; o; o >>= 1) {
    a0 += __shfl_down(a0, o, 64); a1 += __shfl_down(a1, o, 64);
    a2 += __shfl_down(a2, o, 64); a3 += __shfl_down(a3, o, 64);
  }
  if (lane == 0) {
    float4 v = *reinterpret_cast<const float4*>(Vb + (size_t)i * 4);
    float dg = deg[row];
    float r0 = dg * v.x - a0, r1 = dg * v.y - a1;
    float r2 = dg * v.z - a2, r3 = dg * v.w - a3;
    if (mode) {
      r0 = 2.f * r0 + v.x + cs[b * 4 + 0];
      r1 = 2.f * r1 + v.y + cs[b * 4 + 1];
      r2 = 2.f * r2 + v.z + cs[b * 4 + 2];
      r3 = 2.f * r3 + v.w + cs[b * 4 + 3];
    }
    float4 o4 = {r0, r1, r2, r3};
    *reinterpret_cast<float4*>(O + (size_t)row * 4) = o4;
  }
}

// ============ conv1d: [B,N,4] -> [B,N,256], K=5, pad 2 ============
__global__ __launch_bounds__(256) void conv_k(const float* __restrict__ xp,
    const float* __restrict__ w, const float* __restrict__ bias,
    float* __restrict__ x1out) {
  int bn = blockIdx.x;
  int b = bn >> 10, n = bn & 1023;
  int co = threadIdx.x;
  __shared__ float xs[5][4];
  if (threadIdx.x < 20) {
    int k = threadIdx.x >> 2, ci = threadIdx.x & 3;
    int n2 = n + k - 2;
    xs[k][ci] = (n2 >= 0 && n2 < NN) ? xp[((size_t)b * NN + n2) * 4 + ci] : 0.0f;
  }
  __syncthreads();
  const float* wp = w + co * 20;
  float acc = bias[co];
  #pragma unroll
  for (int ci = 0; ci < 4; ++ci)
    #pragma unroll
    for (int k = 0; k < 5; ++k) acc += wp[ci * 5 + k] * xs[k][ci];
  x1out[((size_t)b * NN + n) * CC + co] = acc;
}

// ============ Wasserstein: bitonic sort 1024 per (b,c), sum |s1-s2| ============
__global__ __launch_bounds__(256) void wass_k(const float* __restrict__ x1,
    const float* __restrict__ x2, float* __restrict__ part) {
  int bc = blockIdx.x;
  int b = bc >> 8, c = bc & 255;
  __shared__ float s1[1024];
  __shared__ float s2[1024];
  __shared__ float red[256];
  int t = threadIdx.x;
  for (int q = 0; q < 4; ++q) {
    int n = t + q * 256;
    s1[n] = x1[((size_t)b * NN + n) * CC + c];
    s2[n] = x2[((size_t)b * NN + n) * CC + c];
  }
  __syncthreads();
  for (int k = 2; k <= 1024; k <<= 1) {
    for (int j = k >> 1; j > 0; j >>= 1) {
      #pragma unroll
      for (int q = 0; q < 2; ++q) {
        int idx = t + q * 256;
        int i = ((idx & ~(j - 1)) << 1) | (idx & (j - 1));
        int l = i | j;
        bool up = ((i & k) == 0);
        float a = s1[i], bvv = s1[l];
        if ((a > bvv) == up) { s1[i] = bvv; s1[l] = a; }
        a = s2[i]; bvv = s2[l];
        if ((a > bvv) == up) { s2[i] = bvv; s2[l] = a; }
      }
      __syncthreads();
    }
  }
  float s = 0.f;
  for (int q = 0; q < 4; ++q) {
    int n = t + q * 256;
    s += fabsf(s1[n] - s2[n]);
  }
  red[t] = s;
  __syncthreads();
  for (int o = 128; o; o >>= 1) {
    if (t < o) red[t] += red[t + o];
    __syncthreads();
  }
  if (!t) part[bc] = red[0];
}

// ============ finalize losses ============
__global__ __launch_bounds__(256) void finalize_k(const float* __restrict__ logacc,
    const float* __restrict__ part, float* __restrict__ out) {
  int t = threadIdx.x;
  __shared__ double red[256];
  double s = 0.0;
  for (int i = t; i < 2048; i += 256) s += (double)part[i];
  red[t] = s;
  __syncthreads();
  for (int o = 128; o; o >>= 1) {
    if (t < o) red[t] += red[t + o];
    __syncthreads();
  }
  if (!t) {
    double l1 = 0.0, l2 = 0.0;
    for (int i = 0; i < 8; ++i) { l1 += (double)logacc[i]; l2 += (double)logacc[8 + i]; }
    out[OUT_L + 0] = (float)(-l1 / 8.0);
    out[OUT_L + 1] = (float)(-l2 / 8.0);
    out[OUT_L + 2] = (float)(red[0] / 2097152.0);
  }
}

extern "C" void kernel_launch(void* const* d_in, const int* in_sizes, int n_in,
                              void* d_out, int out_size, void* d_ws, size_t ws_size,
                              hipStream_t stream) {
  (void)in_sizes; (void)n_in; (void)out_size; (void)ws_size;
  const float* G1 = (const float*)d_in[0];
  const float* G2 = (const float*)d_in[1];
  const float* R1 = (const float*)d_in[2];
  const float* R2 = (const float*)d_in[3];
  const float* U1 = (const float*)d_in[7];
  const float* U2 = (const float*)d_in[8];
  const float* CW = (const float*)d_in[9];
  const float* CB = (const float*)d_in[10];
  const float* BG = (const float*)d_in[11];
  const float* BBt = (const float*)d_in[12];
  float* out = (float*)d_out;
  float* ws = (float*)d_ws;

  float* Alu    = ws + OFF_ALU;
  float* logacc = ws + OFF_LOGACC;
  float* deg    = ws + OFF_DEG;
  float* R2n    = ws + OFF_R2N;
  float* LR2    = ws + OFF_LR2;
  float* LR1    = ws + OFF_LR1;
  float* X1P    = ws + OFF_X1P;
  float* CS1    = ws + OFF_CS1;
  float* CS2    = ws + OFF_CS2;
  float* BNP    = ws + OFF_BNP;
  float* BNS    = ws + OFF_BNS;
  float* WSP    = ws + OFF_WSP;
  float* CSP    = ws + OFF_CSP;

  // bf16 scratch lives in the not-yet-written x1 output region (freed before conv_k)
  unsigned short* R2NT = (unsigned short*)(out + OUT_X1);                 // 8*256*1024 bf16 = 1M floats
  unsigned short* LR2T = (unsigned short*)(out + OUT_X1 + 1048576);       // 1M floats

  pool_pair_k<<<dim3(136, 1, 16), 256, 0, stream>>>(G1, G2, U1, U2, out, Alu);
  deg_k<<<4096, 256, 0, stream>>>(out, deg);

  bn_partial_k<<<64, 256, 0, stream>>>(R2, BNP);
  bn_final_k<<<1, 256, 0, stream>>>(BNP, BG, BBt, BNS);
  bn_apply_k<<<8192, 256, 0, stream>>>(R2, BNS, R2n);
  colsum2a_k<<<dim3(16, 8), 256, 0, stream>>>(R2n, CSP);
  colsum2b_k<<<8, 256, 0, stream>>>(CSP, CS2);
  colsum1_k<<<1, 64, 0, stream>>>(R1, CS1);

  // x2 path (MFMA): LR2 = L@R2n ; x2 = 2*L@LR2 + LR2 + cs2
  transp_k<<<dim3(16, 4, 8), 256, 0, stream>>>(R2n, R2NT);
  lgemm_mfma_k<<<dim3(16, 4, 8), 256, 0, stream>>>(out + OUT_G2P, R2NT, R2n,
      deg + 8192, CS2, LR2, LR2T, 0);
  lgemm_mfma_k<<<dim3(16, 4, 8), 256, 0, stream>>>(out + OUT_G2P, LR2T, LR2,
      deg + 8192, CS2, out + OUT_X2, (unsigned short*)0, 1);

  // x1 path (conv_k after lgemm passes: it overwrites the bf16 scratch region)
  gemv4_k<<<2048, 256, 0, stream>>>(out, R1, deg, CS1, LR1, 0);
  gemv4_k<<<2048, 256, 0, stream>>>(out, LR1, deg, CS1, X1P, 1);
  conv_k<<<8192, 256, 0, stream>>>(X1P, CW, CB, out + OUT_X1);

  // blocked UNPIVOTED LU (NB=64)
  for (int p = 0; p < NN / 64; ++p) {
    lu_tiny_k<<<16, 256, 0, stream>>>(Alu, p, logacc);
    int rem = NN - (p + 1) * 64;
    if (rem > 0) {
      int nb = (rem + 255) / 256;
      lu_trsm_k<<<dim3(2 * nb, 16), 256, 0, stream>>>(Alu, p);
      int mt = (rem + 127) / 128;
      lu_gemm64_k<<<dim3(mt, mt, 16), 256, 0, stream>>>(Alu, p);
    }
  }

  wass_k<<<2048, 256, 0, stream>>>(out + OUT_X1, out + OUT_X2, WSP);
  finalize_k<<<1, 256, 0, stream>>>(logacc, WSP, out);
}